// Round 1
// baseline (928.356 us; speedup 1.0000x reference)
//
#include <hip/hip_runtime.h>

// Flow_49160195670664: Dopri5 fixed-step integration of dx/dt = A x + B u(t),
// T=32768, N=256, NI=NO=32, dt=1, Hermite-interpolated stage inputs.
// Linear system => x_{n+1} = R x_n + v_n with constant R; solved via
// 2-level blocked parallel scan (32 x 32 x 32) entirely in fp32.

#define TPTS 32768

struct GemmParams {
  const float* A[16];
  const float* B[16];
  float* C[16];
  int M, K, ksplit, atomic;   // N fixed at 256
};

// C[M][256] (+)= A[M][K] @ B[K][256], row-major, BM=BN=64, BK=16, 4x4 micro-tile.
__global__ __launch_bounds__(256) void gemm_f32(GemmParams p) {
  int bz = blockIdx.z;
  int batch = bz / p.ksplit;
  int split = bz - batch * p.ksplit;
  const float* __restrict__ A = p.A[batch];
  const float* __restrict__ B = p.B[batch];
  float* __restrict__ C = p.C[batch];
  int m0 = blockIdx.x * 64, n0 = blockIdx.y * 64;
  int klen = p.K / p.ksplit;
  int k0 = split * klen;
  __shared__ float As[16][64];
  __shared__ float Bs[16][64];
  int tid = threadIdx.x;
  int tx = tid & 15, ty = tid >> 4;
  int amm = tid >> 2, akk = (tid & 3) << 2;
  int bkk = tid >> 4, bnn = (tid & 15) << 2;
  float acc[4][4] = {{0.f}};
  for (int kt = k0; kt < k0 + klen; kt += 16) {
    float4 av = make_float4(0.f, 0.f, 0.f, 0.f);
    if (m0 + amm < p.M) av = *(const float4*)(A + (size_t)(m0 + amm) * p.K + kt + akk);
    float4 bv = *(const float4*)(B + (size_t)(kt + bkk) * 256 + n0 + bnn);
    __syncthreads();
    As[akk + 0][amm] = av.x;
    As[akk + 1][amm] = av.y;
    As[akk + 2][amm] = av.z;
    As[akk + 3][amm] = av.w;
    *(float4*)&Bs[bkk][bnn] = bv;
    __syncthreads();
#pragma unroll
    for (int kk = 0; kk < 16; kk++) {
      float4 a = *(const float4*)&As[kk][ty << 2];
      float4 b = *(const float4*)&Bs[kk][tx << 2];
      acc[0][0] += a.x * b.x; acc[0][1] += a.x * b.y; acc[0][2] += a.x * b.z; acc[0][3] += a.x * b.w;
      acc[1][0] += a.y * b.x; acc[1][1] += a.y * b.y; acc[1][2] += a.y * b.z; acc[1][3] += a.y * b.w;
      acc[2][0] += a.z * b.x; acc[2][1] += a.z * b.y; acc[2][2] += a.z * b.z; acc[2][3] += a.z * b.w;
      acc[3][0] += a.w * b.x; acc[3][1] += a.w * b.y; acc[3][2] += a.w * b.z; acc[3][3] += a.w * b.w;
    }
  }
  int rbase = m0 + (ty << 2), cbase = n0 + (tx << 2);
  if (p.atomic) {
#pragma unroll
    for (int i2 = 0; i2 < 4; i2++) {
      if (rbase + i2 < p.M) {
#pragma unroll
        for (int j2 = 0; j2 < 4; j2++)
          atomicAdd(&C[(size_t)(rbase + i2) * 256 + cbase + j2], acc[i2][j2]);
      }
    }
  } else {
#pragma unroll
    for (int i2 = 0; i2 < 4; i2++) {
      if (rbase + i2 < p.M)
        *(float4*)&C[(size_t)(rbase + i2) * 256 + cbase] =
            make_float4(acc[i2][0], acc[i2][1], acc[i2][2], acc[i2][3]);
    }
  }
}

// Unit responses through one Dopri5 step (dt=1): columns 0..255 -> R, columns
// 256..383 -> Hermite-folded input tap matrices F_t (t=0..3), stored transposed
// as FcatT[tap][row] for use as GEMM B-operand.
__global__ __launch_bounds__(256) void unit_resp(const float* __restrict__ A,
                                                 const float* __restrict__ Bm,
                                                 float* __restrict__ Rout,
                                                 float* __restrict__ FcatT) {
  int w = blockIdx.x;      // 0..95, 4 columns each
  int i = threadIdx.x;     // row 0..255
  __shared__ float xs4[256][4];

  const float AA[6][5] = {
      {0.f, 0.f, 0.f, 0.f, 0.f},
      {0.2f, 0.f, 0.f, 0.f, 0.f},
      {3.f / 40.f, 9.f / 40.f, 0.f, 0.f, 0.f},
      {44.f / 45.f, -56.f / 15.f, 32.f / 9.f, 0.f, 0.f},
      {19372.f / 6561.f, -25360.f / 2187.f, 64448.f / 6561.f, -212.f / 729.f, 0.f},
      {9017.f / 3168.f, -355.f / 33.f, 46732.f / 5247.f, 49.f / 176.f, -5103.f / 18656.f}};
  const float BB[6] = {35.f / 384.f, 0.f, 500.f / 1113.f, 125.f / 192.f, -2187.f / 6784.f, 11.f / 84.f};
  const float sv[6] = {0.f, 0.2f, 0.3f, 0.8f, 8.f / 9.f, 1.f};
  float Hm[6][4];
#pragma unroll
  for (int s = 0; s < 6; s++) {
    float ss = sv[s], s2 = ss * ss, s3 = s2 * ss;
    Hm[s][0] = 2.f * s3 - 3.f * s2 + 1.f;
    Hm[s][1] = s3 - 2.f * s2 + ss;
    Hm[s][2] = -2.f * s3 + 3.f * s2;
    Hm[s][3] = s3 - s2;
  }

  float xc[4];
  float kreg[6][4];
#pragma unroll
  for (int s = 0; s < 6; s++)
#pragma unroll
    for (int cc = 0; cc < 4; cc++) kreg[s][cc] = 0.f;

  int col[4], isF[4], tt[4];
  float brow[4];
#pragma unroll
  for (int cc = 0; cc < 4; cc++) {
    col[cc] = w * 4 + cc;
    if (col[cc] < 256) {
      isF[cc] = 0; tt[cc] = 0; brow[cc] = 0.f;
      xc[cc] = (i == col[cc]) ? 1.f : 0.f;
    } else {
      isF[cc] = 1; xc[cc] = 0.f;
      int f = col[cc] - 256;
      tt[cc] = f >> 5;
      brow[cc] = Bm[i * 32 + (f & 31)];
    }
  }
  // bh[s][cc] = H[s][t]*B[i][c] contribution injected at stage s
  float bh[6][4];
#pragma unroll
  for (int s = 0; s < 6; s++)
#pragma unroll
    for (int cc = 0; cc < 4; cc++) {
      float hv = (tt[cc] == 0) ? Hm[s][0] : ((tt[cc] == 1) ? Hm[s][1] : ((tt[cc] == 2) ? Hm[s][2] : Hm[s][3]));
      bh[s][cc] = isF[cc] ? hv * brow[cc] : 0.f;
    }

#pragma unroll
  for (int s = 0; s < 6; s++) {
#pragma unroll
    for (int cc = 0; cc < 4; cc++) {
      float v = xc[cc];
#pragma unroll
      for (int j = 0; j < 5; j++)
        if (j < s) v += AA[s][j] * kreg[j][cc];
      xs4[i][cc] = v;
    }
    __syncthreads();
    float ac[4] = {0.f, 0.f, 0.f, 0.f};
    for (int j = 0; j < 256; j += 4) {
      float4 ar = *(const float4*)(A + (size_t)i * 256 + j);
      float4 xa = *(const float4*)xs4[j + 0];
      float4 xb = *(const float4*)xs4[j + 1];
      float4 xv = *(const float4*)xs4[j + 2];
      float4 xd = *(const float4*)xs4[j + 3];
      ac[0] += ar.x * xa.x + ar.y * xb.x + ar.z * xv.x + ar.w * xd.x;
      ac[1] += ar.x * xa.y + ar.y * xb.y + ar.z * xv.y + ar.w * xd.y;
      ac[2] += ar.x * xa.z + ar.y * xb.z + ar.z * xv.z + ar.w * xd.z;
      ac[3] += ar.x * xa.w + ar.y * xb.w + ar.z * xv.w + ar.w * xd.w;
    }
#pragma unroll
    for (int cc = 0; cc < 4; cc++) kreg[s][cc] = ac[cc] + bh[s][cc];
    __syncthreads();
  }
#pragma unroll
  for (int cc = 0; cc < 4; cc++) {
    float o = xc[cc];
#pragma unroll
    for (int s = 0; s < 6; s++) o += BB[s] * kreg[s][cc];
    if (!isF[cc]) Rout[(size_t)i * 256 + col[cc]] = o;
    else FcatT[(size_t)(col[cc] - 256) * 256 + i] = o;
  }
}

// Build W-stack: dst[(slot*256+n)*256 + r] = P[r][n] where P = src[slot] (nullptr => identity)
struct PackParams { const float* src[32]; };
__global__ __launch_bounds__(256) void pack_w(PackParams pp, float* __restrict__ dst) {
  int slot = blockIdx.x;
  int r = threadIdx.x;
  const float* S = pp.src[slot];
  size_t base = (size_t)slot * 256 * 256;
  if (S) {
    for (int n = 0; n < 256; n++) dst[base + (size_t)n * 256 + r] = S[(size_t)r * 256 + n];
  } else {
    for (int n = 0; n < 256; n++) dst[base + (size_t)n * 256 + r] = (r == n) ? 1.f : 0.f;
  }
}

// Wtap[n][tap] = {u_n, m_n, u_{n+1}, m_{n+1}} taps (128 floats); row 32767 = 0 (pad).
__global__ __launch_bounds__(128) void build_wtap(const float* __restrict__ u, float* __restrict__ Wtap) {
  int n = blockIdx.x;
  int tid = threadIdx.x;       // 0..127
  int t = tid >> 5, c = tid & 31;
  float val = 0.f;
  if (n < TPTS - 1) {
    if (t == 0) val = u[(size_t)n * 32 + c];
    else if (t == 2) val = u[(size_t)(n + 1) * 32 + c];
    else {
      int k = (t == 1) ? n : n + 1;
      if (k == 0) val = u[32 + c] - u[c];
      else if (k == TPTS - 1) val = u[(size_t)(TPTS - 1) * 32 + c] - u[(size_t)(TPTS - 2) * 32 + c];
      else val = 0.5f * (u[(size_t)(k + 1) * 32 + c] - u[(size_t)(k - 1) * 32 + c]);
    }
  }
  Wtap[(size_t)n * 128 + tid] = val;
}

// Top-level (stride-1024) starts. ||R1024|| ~ 6e-5 so a 2-term series is exact to ~4e-9:
// X2[0]=x0; X2[1]=V2[0]+R1024 x0; X2[k]=V2[k-1]+R1024 V2[k-2].
__global__ __launch_bounds__(256) void top_scan(const float* __restrict__ V2, const float* __restrict__ x0,
                                                const float* __restrict__ R1024, float* __restrict__ X2) {
  int k = blockIdx.x, i = threadIdx.x;
  if (k == 0) { X2[i] = x0[i]; return; }
  __shared__ float prev[256];
  const float* pv = (k == 1) ? x0 : (V2 + (size_t)(k - 2) * 256);
  prev[i] = pv[i];
  __syncthreads();
  float acc = V2[(size_t)(k - 1) * 256 + i];
  const float* rr = R1024 + (size_t)i * 256;
  for (int j = 0; j < 256; j += 4) {
    float4 rv = *(const float4*)(rr + j);
    acc += rv.x * prev[j] + rv.y * prev[j + 1] + rv.z * prev[j + 2] + rv.w * prev[j + 3];
  }
  X2[(size_t)k * 256 + i] = acc;
}

// Expand one level: per block, 31 sequential steps x <- Rm x + V[row], writing 32 rows.
// Rm cached in registers: 1024 threads = 4 threads/row x 64 cols each.
__global__ __launch_bounds__(1024) void expand_scan(const float* __restrict__ Rm, const float* __restrict__ Xst,
                                                    const float* __restrict__ V, float* __restrict__ Xout) {
  int blk = blockIdx.x;
  int t = threadIdx.x;
  int r = t >> 2, q = t & 3;
  float rg[64];
  const float* rp = Rm + (size_t)r * 256 + q * 64;
#pragma unroll
  for (int l = 0; l < 64; l += 4) {
    float4 v4 = *(const float4*)(rp + l);
    rg[l] = v4.x; rg[l + 1] = v4.y; rg[l + 2] = v4.z; rg[l + 3] = v4.w;
  }
  __shared__ float xc[256];
  __shared__ float red[256][4];
  size_t base = (size_t)blk * 32 * 256;
  if (t < 256) {
    float v = Xst[(size_t)blk * 256 + t];
    xc[t] = v;
    Xout[base + t] = v;
  }
  __syncthreads();
  for (int j = 0; j < 31; j++) {
    float p = 0.f;
    const float* xq = xc + q * 64;
#pragma unroll
    for (int l = 0; l < 64; l += 4) {
      float4 xv = *(const float4*)(xq + l);
      p += rg[l] * xv.x + rg[l + 1] * xv.y + rg[l + 2] * xv.z + rg[l + 3] * xv.w;
    }
    red[r][q] = p;
    __syncthreads();
    if (t < 256) {
      float4 rv = *(const float4*)red[t];
      float nv = rv.x + rv.y + rv.z + rv.w + V[base + (size_t)j * 256 + t];
      xc[t] = nv;
      Xout[base + (size_t)(j + 1) * 256 + t] = nv;
    }
    __syncthreads();
  }
}

// y = x @ C^T + u @ D^T
__global__ __launch_bounds__(256) void y_kernel(const float* __restrict__ x, const float* __restrict__ u,
                                                const float* __restrict__ Cm, const float* __restrict__ Dm,
                                                float* __restrict__ y) {
  __shared__ float Cs[32][260];
  __shared__ float Ds[32][32];
  __shared__ float xs[8][256];
  __shared__ float us[8][32];
  int tid = threadIdx.x;
  for (int k = tid; k < 8192; k += 256) Cs[k >> 8][k & 255] = Cm[k];
  for (int k = tid; k < 1024; k += 256) Ds[k >> 5][k & 31] = Dm[k];
  int o = tid & 31, rr = tid >> 5;
  int n0 = blockIdx.x * 64;
  for (int g = 0; g < 8; g++) {
    int nb = n0 + g * 8;
    __syncthreads();
    for (int k = tid; k < 2048; k += 256)
      xs[k >> 8][k & 255] = x[(size_t)(nb + (k >> 8)) * 256 + (k & 255)];
    for (int k = tid; k < 256; k += 256)
      us[k >> 5][k & 31] = u[(size_t)(nb + (k >> 5)) * 32 + (k & 31)];
    __syncthreads();
    float acc = 0.f;
    for (int i = 0; i < 256; i += 4) {
      float4 cv = *(const float4*)&Cs[o][i];
      float4 xv = *(const float4*)&xs[rr][i];
      acc += cv.x * xv.x + cv.y * xv.y + cv.z * xv.z + cv.w * xv.w;
    }
#pragma unroll
    for (int c = 0; c < 32; c += 4) {
      float4 dv = *(const float4*)&Ds[o][c];
      float4 uv = *(const float4*)&us[rr][c];
      acc += dv.x * uv.x + dv.y * uv.y + dv.z * uv.z + dv.w * uv.w;
    }
    y[(size_t)(nb + rr) * 32 + o] = acc;
  }
}

static void launch_gemm(hipStream_t s, int nb, const float* const* Aa, const float* const* Bb,
                        float* const* Cc, int M, int K, int ksplit, int at) {
  GemmParams p;
  p.M = M; p.K = K; p.ksplit = ksplit; p.atomic = at;
  for (int i = 0; i < nb; i++) { p.A[i] = Aa[i]; p.B[i] = Bb[i]; p.C[i] = Cc[i]; }
  for (int i = nb; i < 16; i++) { p.A[i] = nullptr; p.B[i] = nullptr; p.C[i] = nullptr; }
  dim3 g((M + 63) / 64, 4, nb * ksplit);
  gemm_f32<<<g, dim3(256), 0, s>>>(p);
}

extern "C" void kernel_launch(void* const* d_in, const int* in_sizes, int n_in,
                              void* d_out, int out_size, void* d_ws, size_t ws_size,
                              hipStream_t stream) {
  const float* u  = (const float*)d_in[1];
  const float* x0 = (const float*)d_in[2];
  const float* A  = (const float*)d_in[3];
  const float* Bm = (const float*)d_in[4];
  const float* Cm = (const float*)d_in[5];
  const float* Dm = (const float*)d_in[6];
  float* xout = (float*)d_out;                       // [32768][256]
  float* yout = xout + (size_t)TPTS * 256;           // [32768][32]

  char* wsb = (char*)d_ws;
  size_t off = 0;
  auto alloc = [&](size_t bytes) -> float* {
    float* p = (float*)(wsb + off);
    off = (off + bytes + 255) & ~(size_t)255;
    return p;
  };
  float* Rpow   = alloc(33ull * 65536 * 4);   // slot p = R^p (p=1..32)
  float* R32pow = alloc(33ull * 65536 * 4);   // slot p = R32^p (p=2..32); R32^1 = Rpow[32]
  float* FcatT  = alloc(128ull * 256 * 4);
  float* W1T    = alloc(8192ull * 256 * 4);
  float* W2T    = alloc(8192ull * 256 * 4);
  float* Wtap   = alloc((size_t)TPTS * 128 * 4);
  float* V0     = alloc((size_t)TPTS * 256 * 4);
  float* V1     = alloc(1024ull * 256 * 4);
  float* V2     = alloc(32ull * 256 * 4);
  float* X2     = alloc(32ull * 256 * 4);
  float* X1     = alloc(1024ull * 256 * 4);
  (void)ws_size; (void)in_sizes; (void)n_in; (void)out_size;

  auto RP = [&](int p) -> float* { return Rpow + (size_t)p * 65536; };
  auto QP = [&](int p) -> float* { return R32pow + (size_t)p * 65536; };

  // 1. unit responses -> R (=Rpow[1]) and FcatT
  unit_resp<<<dim3(96), dim3(256), 0, stream>>>(A, Bm, RP(1), FcatT);

  // 2. powers of R (R^2..R^32), doubling-batched
  {
    const float* a[16]; const float* b[16]; float* c[16];
    a[0] = RP(1); b[0] = RP(1); c[0] = RP(2);
    launch_gemm(stream, 1, a, b, c, 256, 256, 1, 0);
    a[0] = RP(2); b[0] = RP(1); c[0] = RP(3);
    a[1] = RP(2); b[1] = RP(2); c[1] = RP(4);
    launch_gemm(stream, 2, a, b, c, 256, 256, 1, 0);
    for (int k = 1; k <= 4; k++) { a[k - 1] = RP(4); b[k - 1] = RP(k); c[k - 1] = RP(4 + k); }
    launch_gemm(stream, 4, a, b, c, 256, 256, 1, 0);
    for (int k = 1; k <= 8; k++) { a[k - 1] = RP(8); b[k - 1] = RP(k); c[k - 1] = RP(8 + k); }
    launch_gemm(stream, 8, a, b, c, 256, 256, 1, 0);
    for (int k = 1; k <= 16; k++) { a[k - 1] = RP(16); b[k - 1] = RP(k); c[k - 1] = RP(16 + k); }
    launch_gemm(stream, 16, a, b, c, 256, 256, 1, 0);
    // powers of R32 (R32^2..R32^32); R32^32 = R^1024
    auto QS = [&](int pp) -> const float* { return (pp == 1) ? (const float*)RP(32) : (const float*)QP(pp); };
    a[0] = QS(1); b[0] = QS(1); c[0] = QP(2);
    launch_gemm(stream, 1, a, b, c, 256, 256, 1, 0);
    a[0] = QP(2); b[0] = QS(1); c[0] = QP(3);
    a[1] = QP(2); b[1] = QP(2); c[1] = QP(4);
    launch_gemm(stream, 2, a, b, c, 256, 256, 1, 0);
    for (int k = 1; k <= 4; k++) { a[k - 1] = QP(4); b[k - 1] = QS(k); c[k - 1] = QP(4 + k); }
    launch_gemm(stream, 4, a, b, c, 256, 256, 1, 0);
    for (int k = 1; k <= 8; k++) { a[k - 1] = QP(8); b[k - 1] = QS(k); c[k - 1] = QP(8 + k); }
    launch_gemm(stream, 8, a, b, c, 256, 256, 1, 0);
    for (int k = 1; k <= 16; k++) { a[k - 1] = QP(16); b[k - 1] = QS(k); c[k - 1] = QP(16 + k); }
    launch_gemm(stream, 16, a, b, c, 256, 256, 1, 0);
  }

  // 3. pack W stacks (transposed, reversed: slot i holds (R^(31-i))^T)
  {
    PackParams w1;
    for (int i = 0; i < 32; i++) { int p = 31 - i; w1.src[i] = (p == 0) ? nullptr : RP(p); }
    pack_w<<<dim3(32), dim3(256), 0, stream>>>(w1, W1T);
    PackParams w2;
    for (int i = 0; i < 32; i++) {
      int p = 31 - i;
      w2.src[i] = (p == 0) ? nullptr : ((p == 1) ? (const float*)RP(32) : (const float*)QP(p));
    }
    pack_w<<<dim3(32), dim3(256), 0, stream>>>(w2, W2T);
  }

  // 4. Hermite taps and per-step drive v_n
  build_wtap<<<dim3(TPTS), dim3(128), 0, stream>>>(u, Wtap);
  {
    const float* a[1] = {Wtap}; const float* b[1] = {FcatT}; float* c[1] = {V0};
    launch_gemm(stream, 1, a, b, c, TPTS, 128, 1, 0);
  }

  // 5. level-1 reduce: V1[j] = sum_i R^(31-i) v_{32j+i}
  hipMemsetAsync(V1, 0, 1024ull * 256 * 4, stream);
  {
    const float* a[1] = {V0}; const float* b[1] = {W1T}; float* c[1] = {V1};
    launch_gemm(stream, 1, a, b, c, 1024, 8192, 8, 1);
  }
  // 6. level-2 reduce: V2[k] = sum_j R32^(31-j) V1[32k+j]
  hipMemsetAsync(V2, 0, 32ull * 256 * 4, stream);
  {
    const float* a[1] = {V1}; const float* b[1] = {W2T}; float* c[1] = {V2};
    launch_gemm(stream, 1, a, b, c, 32, 8192, 8, 1);
  }

  // 7. top starts, then expand down two levels
  top_scan<<<dim3(32), dim3(256), 0, stream>>>(V2, x0, QP(32), X2);
  expand_scan<<<dim3(32), dim3(1024), 0, stream>>>(RP(32), X2, V1, X1);
  expand_scan<<<dim3(1024), dim3(1024), 0, stream>>>(RP(1), X1, V0, xout);

  // 8. outputs y
  y_kernel<<<dim3(512), dim3(256), 0, stream>>>(xout, u, Cm, Dm, yout);
}

// Round 2
// 782.024 us; speedup vs baseline: 1.1871x; 1.1871x over previous
//
#include <hip/hip_runtime.h>

// Flow_49160195670664: Dopri5 fixed-step integration of dx/dt = A x + B u(t),
// T=32768, N=256, NI=NO=32, dt=1, Hermite-interpolated stage inputs.
// Linear system => x_{n+1} = R x_n + v_n with constant R; solved via
// 2-level blocked parallel scan (32 x 32 x 32) entirely in fp32.

#define TPTS 32768

struct GemmParams {
  const float* A[16];
  const float* B[16];
  float* C[16];
  int M, K, ksplit, atomic;   // N fixed at 256
};

// C[M][256] (+)= A[M][K] @ B[K][256], row-major, BM=BN=64, BK=16, 4x4 micro-tile.
__global__ __launch_bounds__(256) void gemm_f32(GemmParams p) {
  int bz = blockIdx.z;
  int batch = bz / p.ksplit;
  int split = bz - batch * p.ksplit;
  const float* __restrict__ A = p.A[batch];
  const float* __restrict__ B = p.B[batch];
  float* __restrict__ C = p.C[batch];
  int m0 = blockIdx.x * 64, n0 = blockIdx.y * 64;
  int klen = p.K / p.ksplit;
  int k0 = split * klen;
  __shared__ float As[16][64];
  __shared__ float Bs[16][64];
  int tid = threadIdx.x;
  int tx = tid & 15, ty = tid >> 4;
  int amm = tid >> 2, akk = (tid & 3) << 2;
  int bkk = tid >> 4, bnn = (tid & 15) << 2;
  float acc[4][4] = {{0.f}};
  for (int kt = k0; kt < k0 + klen; kt += 16) {
    float4 av = make_float4(0.f, 0.f, 0.f, 0.f);
    if (m0 + amm < p.M) av = *(const float4*)(A + (size_t)(m0 + amm) * p.K + kt + akk);
    float4 bv = *(const float4*)(B + (size_t)(kt + bkk) * 256 + n0 + bnn);
    __syncthreads();
    As[akk + 0][amm] = av.x;
    As[akk + 1][amm] = av.y;
    As[akk + 2][amm] = av.z;
    As[akk + 3][amm] = av.w;
    *(float4*)&Bs[bkk][bnn] = bv;
    __syncthreads();
#pragma unroll
    for (int kk = 0; kk < 16; kk++) {
      float4 a = *(const float4*)&As[kk][ty << 2];
      float4 b = *(const float4*)&Bs[kk][tx << 2];
      acc[0][0] += a.x * b.x; acc[0][1] += a.x * b.y; acc[0][2] += a.x * b.z; acc[0][3] += a.x * b.w;
      acc[1][0] += a.y * b.x; acc[1][1] += a.y * b.y; acc[1][2] += a.y * b.z; acc[1][3] += a.y * b.w;
      acc[2][0] += a.z * b.x; acc[2][1] += a.z * b.y; acc[2][2] += a.z * b.z; acc[2][3] += a.z * b.w;
      acc[3][0] += a.w * b.x; acc[3][1] += a.w * b.y; acc[3][2] += a.w * b.z; acc[3][3] += a.w * b.w;
    }
  }
  int rbase = m0 + (ty << 2), cbase = n0 + (tx << 2);
  if (p.atomic) {
#pragma unroll
    for (int i2 = 0; i2 < 4; i2++) {
      if (rbase + i2 < p.M) {
#pragma unroll
        for (int j2 = 0; j2 < 4; j2++)
          atomicAdd(&C[(size_t)(rbase + i2) * 256 + cbase + j2], acc[i2][j2]);
      }
    }
  } else {
#pragma unroll
    for (int i2 = 0; i2 < 4; i2++) {
      if (rbase + i2 < p.M)
        *(float4*)&C[(size_t)(rbase + i2) * 256 + cbase] =
            make_float4(acc[i2][0], acc[i2][1], acc[i2][2], acc[i2][3]);
    }
  }
}

// Unit responses through one Dopri5 step (dt=1): columns 0..255 -> R, columns
// 256..383 -> Hermite-folded input tap matrices F_t (t=0..3), stored transposed
// as FcatT[tap][row] for use as GEMM B-operand.
__global__ __launch_bounds__(256) void unit_resp(const float* __restrict__ A,
                                                 const float* __restrict__ Bm,
                                                 float* __restrict__ Rout,
                                                 float* __restrict__ FcatT) {
  int w = blockIdx.x;      // 0..95, 4 columns each
  int i = threadIdx.x;     // row 0..255
  __shared__ float xs4[256][4];

  const float AA[6][5] = {
      {0.f, 0.f, 0.f, 0.f, 0.f},
      {0.2f, 0.f, 0.f, 0.f, 0.f},
      {3.f / 40.f, 9.f / 40.f, 0.f, 0.f, 0.f},
      {44.f / 45.f, -56.f / 15.f, 32.f / 9.f, 0.f, 0.f},
      {19372.f / 6561.f, -25360.f / 2187.f, 64448.f / 6561.f, -212.f / 729.f, 0.f},
      {9017.f / 3168.f, -355.f / 33.f, 46732.f / 5247.f, 49.f / 176.f, -5103.f / 18656.f}};
  const float BB[6] = {35.f / 384.f, 0.f, 500.f / 1113.f, 125.f / 192.f, -2187.f / 6784.f, 11.f / 84.f};
  const float sv[6] = {0.f, 0.2f, 0.3f, 0.8f, 8.f / 9.f, 1.f};
  float Hm[6][4];
#pragma unroll
  for (int s = 0; s < 6; s++) {
    float ss = sv[s], s2 = ss * ss, s3 = s2 * ss;
    Hm[s][0] = 2.f * s3 - 3.f * s2 + 1.f;
    Hm[s][1] = s3 - 2.f * s2 + ss;
    Hm[s][2] = -2.f * s3 + 3.f * s2;
    Hm[s][3] = s3 - s2;
  }

  float xc[4];
  float kreg[6][4];
#pragma unroll
  for (int s = 0; s < 6; s++)
#pragma unroll
    for (int cc = 0; cc < 4; cc++) kreg[s][cc] = 0.f;

  int col[4], isF[4], tt[4];
  float brow[4];
#pragma unroll
  for (int cc = 0; cc < 4; cc++) {
    col[cc] = w * 4 + cc;
    if (col[cc] < 256) {
      isF[cc] = 0; tt[cc] = 0; brow[cc] = 0.f;
      xc[cc] = (i == col[cc]) ? 1.f : 0.f;
    } else {
      isF[cc] = 1; xc[cc] = 0.f;
      int f = col[cc] - 256;
      tt[cc] = f >> 5;
      brow[cc] = Bm[i * 32 + (f & 31)];
    }
  }
  // bh[s][cc] = H[s][t]*B[i][c] contribution injected at stage s
  float bh[6][4];
#pragma unroll
  for (int s = 0; s < 6; s++)
#pragma unroll
    for (int cc = 0; cc < 4; cc++) {
      float hv = (tt[cc] == 0) ? Hm[s][0] : ((tt[cc] == 1) ? Hm[s][1] : ((tt[cc] == 2) ? Hm[s][2] : Hm[s][3]));
      bh[s][cc] = isF[cc] ? hv * brow[cc] : 0.f;
    }

#pragma unroll
  for (int s = 0; s < 6; s++) {
#pragma unroll
    for (int cc = 0; cc < 4; cc++) {
      float v = xc[cc];
#pragma unroll
      for (int j = 0; j < 5; j++)
        if (j < s) v += AA[s][j] * kreg[j][cc];
      xs4[i][cc] = v;
    }
    __syncthreads();
    float ac[4] = {0.f, 0.f, 0.f, 0.f};
    for (int j = 0; j < 256; j += 4) {
      float4 ar = *(const float4*)(A + (size_t)i * 256 + j);
      float4 xa = *(const float4*)xs4[j + 0];
      float4 xb = *(const float4*)xs4[j + 1];
      float4 xv = *(const float4*)xs4[j + 2];
      float4 xd = *(const float4*)xs4[j + 3];
      ac[0] += ar.x * xa.x + ar.y * xb.x + ar.z * xv.x + ar.w * xd.x;
      ac[1] += ar.x * xa.y + ar.y * xb.y + ar.z * xv.y + ar.w * xd.y;
      ac[2] += ar.x * xa.z + ar.y * xb.z + ar.z * xv.z + ar.w * xd.z;
      ac[3] += ar.x * xa.w + ar.y * xb.w + ar.z * xv.w + ar.w * xd.w;
    }
#pragma unroll
    for (int cc = 0; cc < 4; cc++) kreg[s][cc] = ac[cc] + bh[s][cc];
    __syncthreads();
  }
#pragma unroll
  for (int cc = 0; cc < 4; cc++) {
    float o = xc[cc];
#pragma unroll
    for (int s = 0; s < 6; s++) o += BB[s] * kreg[s][cc];
    if (!isF[cc]) Rout[(size_t)i * 256 + col[cc]] = o;
    else FcatT[(size_t)(col[cc] - 256) * 256 + i] = o;
  }
}

// Build W-stack: dst[(slot*256+n)*256 + r] = P[r][n] where P = src[slot] (nullptr => identity)
struct PackParams { const float* src[32]; };
__global__ __launch_bounds__(256) void pack_w(PackParams pp, float* __restrict__ dst) {
  int slot = blockIdx.x;
  int r = threadIdx.x;
  const float* S = pp.src[slot];
  size_t base = (size_t)slot * 256 * 256;
  if (S) {
    for (int n = 0; n < 256; n++) dst[base + (size_t)n * 256 + r] = S[(size_t)r * 256 + n];
  } else {
    for (int n = 0; n < 256; n++) dst[base + (size_t)n * 256 + r] = (r == n) ? 1.f : 0.f;
  }
}

// Wtap[n][tap] = {u_n, m_n, u_{n+1}, m_{n+1}} taps (128 floats); row 32767 = 0 (pad).
__global__ __launch_bounds__(128) void build_wtap(const float* __restrict__ u, float* __restrict__ Wtap) {
  int n = blockIdx.x;
  int tid = threadIdx.x;       // 0..127
  int t = tid >> 5, c = tid & 31;
  float val = 0.f;
  if (n < TPTS - 1) {
    if (t == 0) val = u[(size_t)n * 32 + c];
    else if (t == 2) val = u[(size_t)(n + 1) * 32 + c];
    else {
      int k = (t == 1) ? n : n + 1;
      if (k == 0) val = u[32 + c] - u[c];
      else if (k == TPTS - 1) val = u[(size_t)(TPTS - 1) * 32 + c] - u[(size_t)(TPTS - 2) * 32 + c];
      else val = 0.5f * (u[(size_t)(k + 1) * 32 + c] - u[(size_t)(k - 1) * 32 + c]);
    }
  }
  Wtap[(size_t)n * 128 + tid] = val;
}

// Top-level (stride-1024) starts. ||R1024|| ~ 6e-5 so a 2-term series is exact to ~4e-9:
// X2[0]=x0; X2[1]=V2[0]+R1024 x0; X2[k]=V2[k-1]+R1024 V2[k-2].
__global__ __launch_bounds__(256) void top_scan(const float* __restrict__ V2, const float* __restrict__ x0,
                                                const float* __restrict__ R1024, float* __restrict__ X2) {
  int k = blockIdx.x, i = threadIdx.x;
  if (k == 0) { X2[i] = x0[i]; return; }
  __shared__ float prev[256];
  const float* pv = (k == 1) ? x0 : (V2 + (size_t)(k - 2) * 256);
  prev[i] = pv[i];
  __syncthreads();
  float acc = V2[(size_t)(k - 1) * 256 + i];
  const float* rr = R1024 + (size_t)i * 256;
  for (int j = 0; j < 256; j += 4) {
    float4 rv = *(const float4*)(rr + j);
    acc += rv.x * prev[j] + rv.y * prev[j + 1] + rv.z * prev[j + 2] + rv.w * prev[j + 3];
  }
  X2[(size_t)k * 256 + i] = acc;
}

// Expand one level: per block, 31 sequential steps x <- Rm x + V[row], writing 32 rows.
// 512 threads: thread t = (row r = t>>1, half q = t&1); R row-half (128 floats) held in
// 32 float4 REGISTERS (launch_bounds(512,2) -> 256-VGPR cap so they actually stay).
// x double-buffered in LDS (one barrier/step); half-slices are 128 floats apart -> the
// two distinct ds_read_b128 addresses alias 2-way, which is free on gfx950 (m136).
// Cross-half reduce via shfl_xor(1) — no LDS scratch, no second barrier.
__global__ __launch_bounds__(512, 2) void expand_scan(const float* __restrict__ Rm, const float* __restrict__ Xst,
                                                      const float* __restrict__ V, float* __restrict__ Xout) {
  int blk = blockIdx.x;
  int t = threadIdx.x;
  int r = t >> 1, q = t & 1;
  float4 rg[32];
  const float* rp = Rm + (size_t)r * 256 + q * 128;
#pragma unroll
  for (int l = 0; l < 32; l++) rg[l] = *(const float4*)(rp + 4 * l);
  __shared__ float xbuf[2][256];
  size_t base = (size_t)blk * 32 * 256;
  if (t < 256) xbuf[0][t] = Xst[(size_t)blk * 256 + t];
  float vnext = 0.f;
  if (q == 0) vnext = V[base + r];           // drive for step j=0
  __syncthreads();
  for (int j = 0; j < 32; j++) {
    const float* cur = xbuf[j & 1];
    if (t < 256) Xout[base + (size_t)j * 256 + t] = cur[t];
    if (j == 31) break;
    float vcur = vnext;
    if (q == 0 && j + 1 < 31) vnext = V[base + (size_t)(j + 1) * 256 + r];
    const float* xq = cur + q * 128;
    float p = 0.f;
#pragma unroll
    for (int l = 0; l < 32; l++) {
      float4 xv = *(const float4*)(xq + 4 * l);
      p += rg[l].x * xv.x + rg[l].y * xv.y + rg[l].z * xv.z + rg[l].w * xv.w;
    }
    p += __shfl_xor(p, 1);
    if (q == 0) xbuf[(j + 1) & 1][r] = p + vcur;
    __syncthreads();
  }
}

// y = x @ C^T + u @ D^T
__global__ __launch_bounds__(256) void y_kernel(const float* __restrict__ x, const float* __restrict__ u,
                                                const float* __restrict__ Cm, const float* __restrict__ Dm,
                                                float* __restrict__ y) {
  __shared__ float Cs[32][260];
  __shared__ float Ds[32][32];
  __shared__ float xs[8][256];
  __shared__ float us[8][32];
  int tid = threadIdx.x;
  for (int k = tid; k < 8192; k += 256) Cs[k >> 8][k & 255] = Cm[k];
  for (int k = tid; k < 1024; k += 256) Ds[k >> 5][k & 31] = Dm[k];
  int o = tid & 31, rr = tid >> 5;
  int n0 = blockIdx.x * 64;
  for (int g = 0; g < 8; g++) {
    int nb = n0 + g * 8;
    __syncthreads();
    for (int k = tid; k < 2048; k += 256)
      xs[k >> 8][k & 255] = x[(size_t)(nb + (k >> 8)) * 256 + (k & 255)];
    for (int k = tid; k < 256; k += 256)
      us[k >> 5][k & 31] = u[(size_t)(nb + (k >> 5)) * 32 + (k & 31)];
    __syncthreads();
    float acc = 0.f;
    for (int i = 0; i < 256; i += 4) {
      float4 cv = *(const float4*)&Cs[o][i];
      float4 xv = *(const float4*)&xs[rr][i];
      acc += cv.x * xv.x + cv.y * xv.y + cv.z * xv.z + cv.w * xv.w;
    }
#pragma unroll
    for (int c = 0; c < 32; c += 4) {
      float4 dv = *(const float4*)&Ds[o][c];
      float4 uv = *(const float4*)&us[rr][c];
      acc += dv.x * uv.x + dv.y * uv.y + dv.z * uv.z + dv.w * uv.w;
    }
    y[(size_t)(nb + rr) * 32 + o] = acc;
  }
}

static void launch_gemm(hipStream_t s, int nb, const float* const* Aa, const float* const* Bb,
                        float* const* Cc, int M, int K, int ksplit, int at) {
  GemmParams p;
  p.M = M; p.K = K; p.ksplit = ksplit; p.atomic = at;
  for (int i = 0; i < nb; i++) { p.A[i] = Aa[i]; p.B[i] = Bb[i]; p.C[i] = Cc[i]; }
  for (int i = nb; i < 16; i++) { p.A[i] = nullptr; p.B[i] = nullptr; p.C[i] = nullptr; }
  dim3 g((M + 63) / 64, 4, nb * ksplit);
  gemm_f32<<<g, dim3(256), 0, s>>>(p);
}

extern "C" void kernel_launch(void* const* d_in, const int* in_sizes, int n_in,
                              void* d_out, int out_size, void* d_ws, size_t ws_size,
                              hipStream_t stream) {
  const float* u  = (const float*)d_in[1];
  const float* x0 = (const float*)d_in[2];
  const float* A  = (const float*)d_in[3];
  const float* Bm = (const float*)d_in[4];
  const float* Cm = (const float*)d_in[5];
  const float* Dm = (const float*)d_in[6];
  float* xout = (float*)d_out;                       // [32768][256]
  float* yout = xout + (size_t)TPTS * 256;           // [32768][32]

  char* wsb = (char*)d_ws;
  size_t off = 0;
  auto alloc = [&](size_t bytes) -> float* {
    float* p = (float*)(wsb + off);
    off = (off + bytes + 255) & ~(size_t)255;
    return p;
  };
  float* Rpow   = alloc(33ull * 65536 * 4);   // slot p = R^p (p=1..32)
  float* R32pow = alloc(33ull * 65536 * 4);   // slot p = R32^p (p=2..32); R32^1 = Rpow[32]
  float* FcatT  = alloc(128ull * 256 * 4);
  float* W1T    = alloc(8192ull * 256 * 4);
  float* W2T    = alloc(8192ull * 256 * 4);
  float* Wtap   = alloc((size_t)TPTS * 128 * 4);
  float* V0     = alloc((size_t)TPTS * 256 * 4);
  float* V1     = alloc(1024ull * 256 * 4);
  float* V2     = alloc(32ull * 256 * 4);
  float* X2     = alloc(32ull * 256 * 4);
  float* X1     = alloc(1024ull * 256 * 4);
  (void)ws_size; (void)in_sizes; (void)n_in; (void)out_size;

  auto RP = [&](int p) -> float* { return Rpow + (size_t)p * 65536; };
  auto QP = [&](int p) -> float* { return R32pow + (size_t)p * 65536; };

  // 1. unit responses -> R (=Rpow[1]) and FcatT
  unit_resp<<<dim3(96), dim3(256), 0, stream>>>(A, Bm, RP(1), FcatT);

  // 2. powers of R (R^2..R^32), doubling-batched
  {
    const float* a[16]; const float* b[16]; float* c[16];
    a[0] = RP(1); b[0] = RP(1); c[0] = RP(2);
    launch_gemm(stream, 1, a, b, c, 256, 256, 1, 0);
    a[0] = RP(2); b[0] = RP(1); c[0] = RP(3);
    a[1] = RP(2); b[1] = RP(2); c[1] = RP(4);
    launch_gemm(stream, 2, a, b, c, 256, 256, 1, 0);
    for (int k = 1; k <= 4; k++) { a[k - 1] = RP(4); b[k - 1] = RP(k); c[k - 1] = RP(4 + k); }
    launch_gemm(stream, 4, a, b, c, 256, 256, 1, 0);
    for (int k = 1; k <= 8; k++) { a[k - 1] = RP(8); b[k - 1] = RP(k); c[k - 1] = RP(8 + k); }
    launch_gemm(stream, 8, a, b, c, 256, 256, 1, 0);
    for (int k = 1; k <= 16; k++) { a[k - 1] = RP(16); b[k - 1] = RP(k); c[k - 1] = RP(16 + k); }
    launch_gemm(stream, 16, a, b, c, 256, 256, 1, 0);
    // powers of R32 (R32^2..R32^32); R32^32 = R^1024
    auto QS = [&](int pp) -> const float* { return (pp == 1) ? (const float*)RP(32) : (const float*)QP(pp); };
    a[0] = QS(1); b[0] = QS(1); c[0] = QP(2);
    launch_gemm(stream, 1, a, b, c, 256, 256, 1, 0);
    a[0] = QP(2); b[0] = QS(1); c[0] = QP(3);
    a[1] = QP(2); b[1] = QP(2); c[1] = QP(4);
    launch_gemm(stream, 2, a, b, c, 256, 256, 1, 0);
    for (int k = 1; k <= 4; k++) { a[k - 1] = QP(4); b[k - 1] = QS(k); c[k - 1] = QP(4 + k); }
    launch_gemm(stream, 4, a, b, c, 256, 256, 1, 0);
    for (int k = 1; k <= 8; k++) { a[k - 1] = QP(8); b[k - 1] = QS(k); c[k - 1] = QP(8 + k); }
    launch_gemm(stream, 8, a, b, c, 256, 256, 1, 0);
    for (int k = 1; k <= 16; k++) { a[k - 1] = QP(16); b[k - 1] = QS(k); c[k - 1] = QP(16 + k); }
    launch_gemm(stream, 16, a, b, c, 256, 256, 1, 0);
  }

  // 3. pack W stacks (transposed, reversed: slot i holds (R^(31-i))^T)
  {
    PackParams w1;
    for (int i = 0; i < 32; i++) { int p = 31 - i; w1.src[i] = (p == 0) ? nullptr : RP(p); }
    pack_w<<<dim3(32), dim3(256), 0, stream>>>(w1, W1T);
    PackParams w2;
    for (int i = 0; i < 32; i++) {
      int p = 31 - i;
      w2.src[i] = (p == 0) ? nullptr : ((p == 1) ? (const float*)RP(32) : (const float*)QP(p));
    }
    pack_w<<<dim3(32), dim3(256), 0, stream>>>(w2, W2T);
  }

  // 4. Hermite taps and per-step drive v_n
  build_wtap<<<dim3(TPTS), dim3(128), 0, stream>>>(u, Wtap);
  {
    const float* a[1] = {Wtap}; const float* b[1] = {FcatT}; float* c[1] = {V0};
    launch_gemm(stream, 1, a, b, c, TPTS, 128, 1, 0);
  }

  // 5. level-1 reduce: V1[j] = sum_i R^(31-i) v_{32j+i}
  hipMemsetAsync(V1, 0, 1024ull * 256 * 4, stream);
  {
    const float* a[1] = {V0}; const float* b[1] = {W1T}; float* c[1] = {V1};
    launch_gemm(stream, 1, a, b, c, 1024, 8192, 8, 1);
  }
  // 6. level-2 reduce: V2[k] = sum_j R32^(31-j) V1[32k+j]
  hipMemsetAsync(V2, 0, 32ull * 256 * 4, stream);
  {
    const float* a[1] = {V1}; const float* b[1] = {W2T}; float* c[1] = {V2};
    launch_gemm(stream, 1, a, b, c, 32, 8192, 8, 1);
  }

  // 7. top starts, then expand down two levels
  top_scan<<<dim3(32), dim3(256), 0, stream>>>(V2, x0, QP(32), X2);
  expand_scan<<<dim3(32), dim3(512), 0, stream>>>(RP(32), X2, V1, X1);
  expand_scan<<<dim3(1024), dim3(512), 0, stream>>>(RP(1), X1, V0, xout);

  // 8. outputs y
  y_kernel<<<dim3(512), dim3(256), 0, stream>>>(xout, u, Cm, Dm, yout);
}

// Round 3
// 744.507 us; speedup vs baseline: 1.2469x; 1.0504x over previous
//
#include <hip/hip_runtime.h>

// Flow_49160195670664: Dopri5 fixed-step integration of dx/dt = A x + B u(t),
// T=32768, N=256, NI=NO=32, dt=1, Hermite-interpolated stage inputs.
// Linear system => x_{n+1} = R x_n + v_n with constant R; solved via
// 2-level blocked parallel scan (32 x 32 x 32) entirely in fp32.

#define TPTS 32768

struct GemmParams {
  const float* A[16];
  const float* B[16];
  float* C[16];
  int M, K, ksplit, atomic;   // N fixed at 256
};

// C[M][256] (+)= A[M][K] @ B[K][256], row-major, BM=BN=64, BK=16, 4x4 micro-tile.
// Used for the small R-power ladder and V2 reduce (proven correct; low risk).
__global__ __launch_bounds__(256) void gemm_f32(GemmParams p) {
  int bz = blockIdx.z;
  int batch = bz / p.ksplit;
  int split = bz - batch * p.ksplit;
  const float* __restrict__ A = p.A[batch];
  const float* __restrict__ B = p.B[batch];
  float* __restrict__ C = p.C[batch];
  int m0 = blockIdx.x * 64, n0 = blockIdx.y * 64;
  int klen = p.K / p.ksplit;
  int k0 = split * klen;
  __shared__ float As[16][64];
  __shared__ float Bs[16][64];
  int tid = threadIdx.x;
  int tx = tid & 15, ty = tid >> 4;
  int amm = tid >> 2, akk = (tid & 3) << 2;
  int bkk = tid >> 4, bnn = (tid & 15) << 2;
  float acc[4][4] = {{0.f}};
  for (int kt = k0; kt < k0 + klen; kt += 16) {
    float4 av = make_float4(0.f, 0.f, 0.f, 0.f);
    if (m0 + amm < p.M) av = *(const float4*)(A + (size_t)(m0 + amm) * p.K + kt + akk);
    float4 bv = *(const float4*)(B + (size_t)(kt + bkk) * 256 + n0 + bnn);
    __syncthreads();
    As[akk + 0][amm] = av.x;
    As[akk + 1][amm] = av.y;
    As[akk + 2][amm] = av.z;
    As[akk + 3][amm] = av.w;
    *(float4*)&Bs[bkk][bnn] = bv;
    __syncthreads();
#pragma unroll
    for (int kk = 0; kk < 16; kk++) {
      float4 a = *(const float4*)&As[kk][ty << 2];
      float4 b = *(const float4*)&Bs[kk][tx << 2];
      acc[0][0] += a.x * b.x; acc[0][1] += a.x * b.y; acc[0][2] += a.x * b.z; acc[0][3] += a.x * b.w;
      acc[1][0] += a.y * b.x; acc[1][1] += a.y * b.y; acc[1][2] += a.y * b.z; acc[1][3] += a.y * b.w;
      acc[2][0] += a.z * b.x; acc[2][1] += a.z * b.y; acc[2][2] += a.z * b.z; acc[2][3] += a.z * b.w;
      acc[3][0] += a.w * b.x; acc[3][1] += a.w * b.y; acc[3][2] += a.w * b.z; acc[3][3] += a.w * b.w;
    }
  }
  int rbase = m0 + (ty << 2), cbase = n0 + (tx << 2);
  if (p.atomic) {
#pragma unroll
    for (int i2 = 0; i2 < 4; i2++) {
      if (rbase + i2 < p.M) {
#pragma unroll
        for (int j2 = 0; j2 < 4; j2++)
          atomicAdd(&C[(size_t)(rbase + i2) * 256 + cbase + j2], acc[i2][j2]);
      }
    }
  } else {
#pragma unroll
    for (int i2 = 0; i2 < 4; i2++) {
      if (rbase + i2 < p.M)
        *(float4*)&C[(size_t)(rbase + i2) * 256 + cbase] =
            make_float4(acc[i2][0], acc[i2][1], acc[i2][2], acc[i2][3]);
    }
  }
}

// High-throughput fp32 GEMM: C[M][256] = A[M][K] @ B[K][256] (N fixed 256),
// BM=BN=128, BK=8, 256 threads, 8x8 micro-tile (VALU-bound, ~4 MAC/LDS-float).
// Split-K writes partials to C + split*cstride (deterministic; no atomics).
__global__ __launch_bounds__(256) void gemm128(const float* __restrict__ A, const float* __restrict__ B,
                                               float* __restrict__ C, int M, int K, int ksplit,
                                               size_t cstride) {
  int m0 = blockIdx.x * 128, n0 = blockIdx.y * 128;
  int split = blockIdx.z;
  int klen = K / ksplit;
  int k0 = split * klen;
  float* __restrict__ Cw = C + (size_t)split * cstride;
  __shared__ float As[8][128];
  __shared__ float Bs[8][128];
  int tid = threadIdx.x;
  int am = tid >> 1, akc = (tid & 1) * 4;      // A: row am, k-chunk akc
  int bk = tid >> 5, bn = (tid & 31) * 4;      // B: k bk, col-chunk bn
  int ty = tid >> 4, tx = tid & 15;            // micro-tile: rows 8*ty.., cols 8*tx..
  float acc[8][8] = {{0.f}};
  for (int kt = k0; kt < k0 + klen; kt += 8) {
    float4 av = make_float4(0.f, 0.f, 0.f, 0.f);
    if (m0 + am < M) av = *(const float4*)(A + (size_t)(m0 + am) * K + kt + akc);
    float4 bv = *(const float4*)(B + (size_t)(kt + bk) * 256 + n0 + bn);
    __syncthreads();
    As[akc + 0][am] = av.x;
    As[akc + 1][am] = av.y;
    As[akc + 2][am] = av.z;
    As[akc + 3][am] = av.w;
    *(float4*)&Bs[bk][bn] = bv;
    __syncthreads();
#pragma unroll
    for (int kk = 0; kk < 8; kk++) {
      float4 a0 = *(const float4*)&As[kk][ty * 8];
      float4 a1 = *(const float4*)&As[kk][ty * 8 + 4];
      float4 b0 = *(const float4*)&Bs[kk][tx * 8];
      float4 b1 = *(const float4*)&Bs[kk][tx * 8 + 4];
      float ar[8] = {a0.x, a0.y, a0.z, a0.w, a1.x, a1.y, a1.z, a1.w};
      float br[8] = {b0.x, b0.y, b0.z, b0.w, b1.x, b1.y, b1.z, b1.w};
#pragma unroll
      for (int i = 0; i < 8; i++)
#pragma unroll
        for (int j = 0; j < 8; j++) acc[i][j] += ar[i] * br[j];
    }
  }
#pragma unroll
  for (int i = 0; i < 8; i++) {
    int row = m0 + ty * 8 + i;
    if (row < M) {
      *(float4*)&Cw[(size_t)row * 256 + n0 + tx * 8] = make_float4(acc[i][0], acc[i][1], acc[i][2], acc[i][3]);
      *(float4*)&Cw[(size_t)row * 256 + n0 + tx * 8 + 4] = make_float4(acc[i][4], acc[i][5], acc[i][6], acc[i][7]);
    }
  }
}

// dst[i] = sum over nsplit of src[s*elems + i]; elems multiple of 1024.
__global__ __launch_bounds__(256) void reduce_splits(const float* __restrict__ src, float* __restrict__ dst,
                                                     int nsplit, int elems) {
  int idx = (blockIdx.x * 256 + threadIdx.x) * 4;
  if (idx >= elems) return;
  float4 a = make_float4(0.f, 0.f, 0.f, 0.f);
  for (int s = 0; s < nsplit; s++) {
    float4 v = *(const float4*)(src + (size_t)s * elems + idx);
    a.x += v.x; a.y += v.y; a.z += v.z; a.w += v.w;
  }
  *(float4*)(dst + idx) = a;
}

// Unit responses through one Dopri5 step (dt=1): columns 0..255 -> R, columns
// 256..383 -> Hermite-folded input tap matrices F_t (t=0..3), stored transposed
// as FcatT[tap][row] for use as GEMM B-operand.
__global__ __launch_bounds__(256) void unit_resp(const float* __restrict__ A,
                                                 const float* __restrict__ Bm,
                                                 float* __restrict__ Rout,
                                                 float* __restrict__ FcatT) {
  int w = blockIdx.x;      // 0..95, 4 columns each
  int i = threadIdx.x;     // row 0..255
  __shared__ float xs4[256][4];

  const float AA[6][5] = {
      {0.f, 0.f, 0.f, 0.f, 0.f},
      {0.2f, 0.f, 0.f, 0.f, 0.f},
      {3.f / 40.f, 9.f / 40.f, 0.f, 0.f, 0.f},
      {44.f / 45.f, -56.f / 15.f, 32.f / 9.f, 0.f, 0.f},
      {19372.f / 6561.f, -25360.f / 2187.f, 64448.f / 6561.f, -212.f / 729.f, 0.f},
      {9017.f / 3168.f, -355.f / 33.f, 46732.f / 5247.f, 49.f / 176.f, -5103.f / 18656.f}};
  const float BB[6] = {35.f / 384.f, 0.f, 500.f / 1113.f, 125.f / 192.f, -2187.f / 6784.f, 11.f / 84.f};
  const float sv[6] = {0.f, 0.2f, 0.3f, 0.8f, 8.f / 9.f, 1.f};
  float Hm[6][4];
#pragma unroll
  for (int s = 0; s < 6; s++) {
    float ss = sv[s], s2 = ss * ss, s3 = s2 * ss;
    Hm[s][0] = 2.f * s3 - 3.f * s2 + 1.f;
    Hm[s][1] = s3 - 2.f * s2 + ss;
    Hm[s][2] = -2.f * s3 + 3.f * s2;
    Hm[s][3] = s3 - s2;
  }

  float xc[4];
  float kreg[6][4];
#pragma unroll
  for (int s = 0; s < 6; s++)
#pragma unroll
    for (int cc = 0; cc < 4; cc++) kreg[s][cc] = 0.f;

  int col[4], isF[4], tt[4];
  float brow[4];
#pragma unroll
  for (int cc = 0; cc < 4; cc++) {
    col[cc] = w * 4 + cc;
    if (col[cc] < 256) {
      isF[cc] = 0; tt[cc] = 0; brow[cc] = 0.f;
      xc[cc] = (i == col[cc]) ? 1.f : 0.f;
    } else {
      isF[cc] = 1; xc[cc] = 0.f;
      int f = col[cc] - 256;
      tt[cc] = f >> 5;
      brow[cc] = Bm[i * 32 + (f & 31)];
    }
  }
  // bh[s][cc] = H[s][t]*B[i][c] contribution injected at stage s
  float bh[6][4];
#pragma unroll
  for (int s = 0; s < 6; s++)
#pragma unroll
    for (int cc = 0; cc < 4; cc++) {
      float hv = (tt[cc] == 0) ? Hm[s][0] : ((tt[cc] == 1) ? Hm[s][1] : ((tt[cc] == 2) ? Hm[s][2] : Hm[s][3]));
      bh[s][cc] = isF[cc] ? hv * brow[cc] : 0.f;
    }

#pragma unroll
  for (int s = 0; s < 6; s++) {
#pragma unroll
    for (int cc = 0; cc < 4; cc++) {
      float v = xc[cc];
#pragma unroll
      for (int j = 0; j < 5; j++)
        if (j < s) v += AA[s][j] * kreg[j][cc];
      xs4[i][cc] = v;
    }
    __syncthreads();
    float ac[4] = {0.f, 0.f, 0.f, 0.f};
    for (int j = 0; j < 256; j += 4) {
      float4 ar = *(const float4*)(A + (size_t)i * 256 + j);
      float4 xa = *(const float4*)xs4[j + 0];
      float4 xb = *(const float4*)xs4[j + 1];
      float4 xv = *(const float4*)xs4[j + 2];
      float4 xd = *(const float4*)xs4[j + 3];
      ac[0] += ar.x * xa.x + ar.y * xb.x + ar.z * xv.x + ar.w * xd.x;
      ac[1] += ar.x * xa.y + ar.y * xb.y + ar.z * xv.y + ar.w * xd.y;
      ac[2] += ar.x * xa.z + ar.y * xb.z + ar.z * xv.z + ar.w * xd.z;
      ac[3] += ar.x * xa.w + ar.y * xb.w + ar.z * xv.w + ar.w * xd.w;
    }
#pragma unroll
    for (int cc = 0; cc < 4; cc++) kreg[s][cc] = ac[cc] + bh[s][cc];
    __syncthreads();
  }
#pragma unroll
  for (int cc = 0; cc < 4; cc++) {
    float o = xc[cc];
#pragma unroll
    for (int s = 0; s < 6; s++) o += BB[s] * kreg[s][cc];
    if (!isF[cc]) Rout[(size_t)i * 256 + col[cc]] = o;
    else FcatT[(size_t)(col[cc] - 256) * 256 + i] = o;
  }
}

// Build W-stack: dst[(slot*256+n)*256 + r] = P[r][n] where P = src[slot] (nullptr => identity)
struct PackParams { const float* src[32]; };
__global__ __launch_bounds__(256) void pack_w(PackParams pp, float* __restrict__ dst) {
  int slot = blockIdx.x;
  int r = threadIdx.x;
  const float* S = pp.src[slot];
  size_t base = (size_t)slot * 256 * 256;
  if (S) {
    for (int n = 0; n < 256; n++) dst[base + (size_t)n * 256 + r] = S[(size_t)r * 256 + n];
  } else {
    for (int n = 0; n < 256; n++) dst[base + (size_t)n * 256 + r] = (r == n) ? 1.f : 0.f;
  }
}

// Wtap[n][tap] = {u_n, m_n, u_{n+1}, m_{n+1}} taps (128 floats); row 32767 = 0 (pad).
__global__ __launch_bounds__(128) void build_wtap(const float* __restrict__ u, float* __restrict__ Wtap) {
  int n = blockIdx.x;
  int tid = threadIdx.x;       // 0..127
  int t = tid >> 5, c = tid & 31;
  float val = 0.f;
  if (n < TPTS - 1) {
    if (t == 0) val = u[(size_t)n * 32 + c];
    else if (t == 2) val = u[(size_t)(n + 1) * 32 + c];
    else {
      int k = (t == 1) ? n : n + 1;
      if (k == 0) val = u[32 + c] - u[c];
      else if (k == TPTS - 1) val = u[(size_t)(TPTS - 1) * 32 + c] - u[(size_t)(TPTS - 2) * 32 + c];
      else val = 0.5f * (u[(size_t)(k + 1) * 32 + c] - u[(size_t)(k - 1) * 32 + c]);
    }
  }
  Wtap[(size_t)n * 128 + tid] = val;
}

// Top-level (stride-1024) starts. ||R1024|| ~ 6e-5 so a 2-term series is exact to ~4e-9:
// X2[0]=x0; X2[1]=V2[0]+R1024 x0; X2[k]=V2[k-1]+R1024 V2[k-2].
__global__ __launch_bounds__(256) void top_scan(const float* __restrict__ V2, const float* __restrict__ x0,
                                                const float* __restrict__ R1024, float* __restrict__ X2) {
  int k = blockIdx.x, i = threadIdx.x;
  if (k == 0) { X2[i] = x0[i]; return; }
  __shared__ float prev[256];
  const float* pv = (k == 1) ? x0 : (V2 + (size_t)(k - 2) * 256);
  prev[i] = pv[i];
  __syncthreads();
  float acc = V2[(size_t)(k - 1) * 256 + i];
  const float* rr = R1024 + (size_t)i * 256;
  for (int j = 0; j < 256; j += 4) {
    float4 rv = *(const float4*)(rr + j);
    acc += rv.x * prev[j] + rv.y * prev[j + 1] + rv.z * prev[j + 2] + rv.w * prev[j + 3];
  }
  X2[(size_t)k * 256 + i] = acc;
}

// Expand one level: per block, 31 sequential steps x <- Rm x + V[row], writing 32 rows.
// 512 threads = 8 waves; wave w owns rows [32w,32w+32). Lane l: rowgroup rg=l>>3 (4 rows),
// colgroup cg=l&7 (32 cols). R slice = 32 float4 in REGISTERS, pinned by an asm memory
// clobber (prevents the compiler sinking the loads into the step loop — the round-2
// failure mode, VGPR=80). x reads from LDS use a rg-rotation so each wave instruction
// reads 64 distinct float4 (full LDS BW, no conflicts). Cross-colgroup reduction via
// 3x shfl_xor; one barrier per step; x double-buffered in LDS.
__global__ __launch_bounds__(512, 2) void expand_scan(const float* __restrict__ Rm, const float* __restrict__ Xst,
                                                      const float* __restrict__ V, float* __restrict__ Xout) {
  int blk = blockIdx.x;
  int t = threadIdx.x;
  int w = t >> 6, l = t & 63;
  int rg = l >> 3, cg = l & 7;
  int r0 = w * 32 + rg * 4;
  float4 rr[4][8];
#pragma unroll
  for (int row = 0; row < 4; row++)
#pragma unroll
    for (int i = 0; i < 8; i++) {
      int col = cg * 32 + (((i + rg) & 7) << 2);
      rr[row][i] = *(const float4*)(Rm + (size_t)(r0 + row) * 256 + col);
    }
  asm volatile("" ::: "memory");   // pin rr in registers: loads cannot be re-issued later
  __shared__ float xbuf[2][256];
  size_t base = (size_t)blk * 32 * 256;
  if (t < 64) *(float4*)&xbuf[0][t * 4] = *(const float4*)(Xst + (size_t)blk * 256 + t * 4);
  __syncthreads();
  for (int j = 0; j < 32; j++) {
    float* cur = xbuf[j & 1];
    if (t < 64) *(float4*)(Xout + base + (size_t)j * 256 + t * 4) = *(const float4*)(cur + t * 4);
    if (j == 31) break;
    float4 vdrv = make_float4(0.f, 0.f, 0.f, 0.f);
    if (cg == 0) vdrv = *(const float4*)(V + base + (size_t)j * 256 + r0);
    float4 p = make_float4(0.f, 0.f, 0.f, 0.f);
#pragma unroll
    for (int i = 0; i < 8; i++) {
      int col = cg * 32 + (((i + rg) & 7) << 2);
      float4 xv = *(const float4*)(cur + col);
      p.x += rr[0][i].x * xv.x + rr[0][i].y * xv.y + rr[0][i].z * xv.z + rr[0][i].w * xv.w;
      p.y += rr[1][i].x * xv.x + rr[1][i].y * xv.y + rr[1][i].z * xv.z + rr[1][i].w * xv.w;
      p.z += rr[2][i].x * xv.x + rr[2][i].y * xv.y + rr[2][i].z * xv.z + rr[2][i].w * xv.w;
      p.w += rr[3][i].x * xv.x + rr[3][i].y * xv.y + rr[3][i].z * xv.z + rr[3][i].w * xv.w;
    }
#pragma unroll
    for (int m = 1; m < 8; m <<= 1) {
      p.x += __shfl_xor(p.x, m);
      p.y += __shfl_xor(p.y, m);
      p.z += __shfl_xor(p.z, m);
      p.w += __shfl_xor(p.w, m);
    }
    if (cg == 0) {
      p.x += vdrv.x; p.y += vdrv.y; p.z += vdrv.z; p.w += vdrv.w;
      *(float4*)&xbuf[(j + 1) & 1][r0] = p;
    }
    __syncthreads();
  }
}

// y = x @ C^T + u @ D^T
__global__ __launch_bounds__(256) void y_kernel(const float* __restrict__ x, const float* __restrict__ u,
                                                const float* __restrict__ Cm, const float* __restrict__ Dm,
                                                float* __restrict__ y) {
  __shared__ float Cs[32][260];
  __shared__ float Ds[32][32];
  __shared__ float xs[8][256];
  __shared__ float us[8][32];
  int tid = threadIdx.x;
  for (int k = tid; k < 8192; k += 256) Cs[k >> 8][k & 255] = Cm[k];
  for (int k = tid; k < 1024; k += 256) Ds[k >> 5][k & 31] = Dm[k];
  int o = tid & 31, rr = tid >> 5;
  int n0 = blockIdx.x * 64;
  for (int g = 0; g < 8; g++) {
    int nb = n0 + g * 8;
    __syncthreads();
    for (int k = tid; k < 2048; k += 256)
      xs[k >> 8][k & 255] = x[(size_t)(nb + (k >> 8)) * 256 + (k & 255)];
    for (int k = tid; k < 256; k += 256)
      us[k >> 5][k & 31] = u[(size_t)(nb + (k >> 5)) * 32 + (k & 31)];
    __syncthreads();
    float acc = 0.f;
    for (int i = 0; i < 256; i += 4) {
      float4 cv = *(const float4*)&Cs[o][i];
      float4 xv = *(const float4*)&xs[rr][i];
      acc += cv.x * xv.x + cv.y * xv.y + cv.z * xv.z + cv.w * xv.w;
    }
#pragma unroll
    for (int c = 0; c < 32; c += 4) {
      float4 dv = *(const float4*)&Ds[o][c];
      float4 uv = *(const float4*)&us[rr][c];
      acc += dv.x * uv.x + dv.y * uv.y + dv.z * uv.z + dv.w * uv.w;
    }
    y[(size_t)(nb + rr) * 32 + o] = acc;
  }
}

static void launch_gemm(hipStream_t s, int nb, const float* const* Aa, const float* const* Bb,
                        float* const* Cc, int M, int K, int ksplit, int at) {
  GemmParams p;
  p.M = M; p.K = K; p.ksplit = ksplit; p.atomic = at;
  for (int i = 0; i < nb; i++) { p.A[i] = Aa[i]; p.B[i] = Bb[i]; p.C[i] = Cc[i]; }
  for (int i = nb; i < 16; i++) { p.A[i] = nullptr; p.B[i] = nullptr; p.C[i] = nullptr; }
  dim3 g((M + 63) / 64, 4, nb * ksplit);
  gemm_f32<<<g, dim3(256), 0, s>>>(p);
}

extern "C" void kernel_launch(void* const* d_in, const int* in_sizes, int n_in,
                              void* d_out, int out_size, void* d_ws, size_t ws_size,
                              hipStream_t stream) {
  const float* u  = (const float*)d_in[1];
  const float* x0 = (const float*)d_in[2];
  const float* A  = (const float*)d_in[3];
  const float* Bm = (const float*)d_in[4];
  const float* Cm = (const float*)d_in[5];
  const float* Dm = (const float*)d_in[6];
  float* xout = (float*)d_out;                       // [32768][256]
  float* yout = xout + (size_t)TPTS * 256;           // [32768][32]

  char* wsb = (char*)d_ws;
  size_t off = 0;
  auto alloc = [&](size_t bytes) -> float* {
    float* p = (float*)(wsb + off);
    off = (off + bytes + 255) & ~(size_t)255;
    return p;
  };
  float* Rpow   = alloc(33ull * 65536 * 4);   // slot p = R^p (p=1..32)
  float* R32pow = alloc(33ull * 65536 * 4);   // slot p = R32^p (p=2..32); R32^1 = Rpow[32]
  float* FcatT  = alloc(128ull * 256 * 4);
  float* W1T    = alloc(8192ull * 256 * 4);
  float* W2T    = alloc(8192ull * 256 * 4);
  float* Wtap   = alloc((size_t)TPTS * 128 * 4);
  float* V0     = alloc((size_t)TPTS * 256 * 4);
  float* V1     = alloc(1024ull * 256 * 4);
  float* V1p    = alloc(16ull * 1024 * 256 * 4);   // split-K partials for V1 reduce
  float* V2     = alloc(32ull * 256 * 4);
  float* X2     = alloc(32ull * 256 * 4);
  float* X1     = alloc(1024ull * 256 * 4);
  (void)ws_size; (void)in_sizes; (void)n_in; (void)out_size;

  auto RP = [&](int p) -> float* { return Rpow + (size_t)p * 65536; };
  auto QP = [&](int p) -> float* { return R32pow + (size_t)p * 65536; };

  // 1. unit responses -> R (=Rpow[1]) and FcatT
  unit_resp<<<dim3(96), dim3(256), 0, stream>>>(A, Bm, RP(1), FcatT);

  // 2. powers of R (R^2..R^32), doubling-batched
  {
    const float* a[16]; const float* b[16]; float* c[16];
    a[0] = RP(1); b[0] = RP(1); c[0] = RP(2);
    launch_gemm(stream, 1, a, b, c, 256, 256, 1, 0);
    a[0] = RP(2); b[0] = RP(1); c[0] = RP(3);
    a[1] = RP(2); b[1] = RP(2); c[1] = RP(4);
    launch_gemm(stream, 2, a, b, c, 256, 256, 1, 0);
    for (int k = 1; k <= 4; k++) { a[k - 1] = RP(4); b[k - 1] = RP(k); c[k - 1] = RP(4 + k); }
    launch_gemm(stream, 4, a, b, c, 256, 256, 1, 0);
    for (int k = 1; k <= 8; k++) { a[k - 1] = RP(8); b[k - 1] = RP(k); c[k - 1] = RP(8 + k); }
    launch_gemm(stream, 8, a, b, c, 256, 256, 1, 0);
    for (int k = 1; k <= 16; k++) { a[k - 1] = RP(16); b[k - 1] = RP(k); c[k - 1] = RP(16 + k); }
    launch_gemm(stream, 16, a, b, c, 256, 256, 1, 0);
    // powers of R32 (R32^2..R32^32); R32^32 = R^1024
    auto QS = [&](int pp) -> const float* { return (pp == 1) ? (const float*)RP(32) : (const float*)QP(pp); };
    a[0] = QS(1); b[0] = QS(1); c[0] = QP(2);
    launch_gemm(stream, 1, a, b, c, 256, 256, 1, 0);
    a[0] = QP(2); b[0] = QS(1); c[0] = QP(3);
    a[1] = QP(2); b[1] = QP(2); c[1] = QP(4);
    launch_gemm(stream, 2, a, b, c, 256, 256, 1, 0);
    for (int k = 1; k <= 4; k++) { a[k - 1] = QP(4); b[k - 1] = QS(k); c[k - 1] = QP(4 + k); }
    launch_gemm(stream, 4, a, b, c, 256, 256, 1, 0);
    for (int k = 1; k <= 8; k++) { a[k - 1] = QP(8); b[k - 1] = QS(k); c[k - 1] = QP(8 + k); }
    launch_gemm(stream, 8, a, b, c, 256, 256, 1, 0);
    for (int k = 1; k <= 16; k++) { a[k - 1] = QP(16); b[k - 1] = QS(k); c[k - 1] = QP(16 + k); }
    launch_gemm(stream, 16, a, b, c, 256, 256, 1, 0);
  }

  // 3. pack W stacks (transposed, reversed: slot i holds (R^(31-i))^T)
  {
    PackParams w1;
    for (int i = 0; i < 32; i++) { int p = 31 - i; w1.src[i] = (p == 0) ? nullptr : RP(p); }
    pack_w<<<dim3(32), dim3(256), 0, stream>>>(w1, W1T);
    PackParams w2;
    for (int i = 0; i < 32; i++) {
      int p = 31 - i;
      w2.src[i] = (p == 0) ? nullptr : ((p == 1) ? (const float*)RP(32) : (const float*)QP(p));
    }
    pack_w<<<dim3(32), dim3(256), 0, stream>>>(w2, W2T);
  }

  // 4. Hermite taps and per-step drive v_n  (V0 = Wtap @ FcatT^T-stack, K=128)
  build_wtap<<<dim3(TPTS), dim3(128), 0, stream>>>(u, Wtap);
  gemm128<<<dim3(256, 2, 1), dim3(256), 0, stream>>>(Wtap, FcatT, V0, TPTS, 128, 1, 0);

  // 5. level-1 reduce: V1[j] = sum_i R^(31-i) v_{32j+i}  (split-K=16 partials + reduce)
  gemm128<<<dim3(8, 2, 16), dim3(256), 0, stream>>>(V0, W1T, V1p, 1024, 8192, 16, (size_t)1024 * 256);
  reduce_splits<<<dim3(256), dim3(256), 0, stream>>>(V1p, V1, 16, 1024 * 256);

  // 6. level-2 reduce: V2[k] = sum_j R32^(31-j) V1[32k+j]  (small; proven atomic path)
  hipMemsetAsync(V2, 0, 32ull * 256 * 4, stream);
  {
    const float* a[1] = {V1}; const float* b[1] = {W2T}; float* c[1] = {V2};
    launch_gemm(stream, 1, a, b, c, 32, 8192, 8, 1);
  }

  // 7. top starts, then expand down two levels
  top_scan<<<dim3(32), dim3(256), 0, stream>>>(V2, x0, QP(32), X2);
  expand_scan<<<dim3(32), dim3(512), 0, stream>>>(RP(32), X2, V1, X1);
  expand_scan<<<dim3(1024), dim3(512), 0, stream>>>(RP(1), X1, V0, xout);

  // 8. outputs y
  y_kernel<<<dim3(512), dim3(256), 0, stream>>>(xout, u, Cm, Dm, yout);
}

// Round 4
// 699.825 us; speedup vs baseline: 1.3266x; 1.0638x over previous
//
#include <hip/hip_runtime.h>

// Flow_49160195670664: Dopri5 fixed-step integration of dx/dt = A x + B u(t),
// T=32768, N=256, NI=NO=32, dt=1, Hermite-interpolated stage inputs.
// Linear system => x_{n+1} = R x_n + v_n with constant R; 2-level blocked
// parallel scan (32 x 32 x 32), fp32 throughout.

#define TPTS 32768

struct GemmParams {
  const float* A[16];
  const float* B[16];
  float* C[16];
  float* Ct[16];              // optional transposed store (for W-stack fusion)
  int M, K, ksplit, atomic;   // N fixed at 256
};

// C[M][256] (+)= A[M][K] @ B[K][256], row-major, BM=BN=64, BK=16, 4x4 micro-tile.
// If Ct[batch] set, also stores C^T there (kills the pack_w transpose pass).
__global__ __launch_bounds__(256) void gemm_f32(GemmParams p) {
  int bz = blockIdx.z;
  int batch = bz / p.ksplit;
  int split = bz - batch * p.ksplit;
  const float* __restrict__ A = p.A[batch];
  const float* __restrict__ B = p.B[batch];
  float* __restrict__ C = p.C[batch];
  int m0 = blockIdx.x * 64, n0 = blockIdx.y * 64;
  int klen = p.K / p.ksplit;
  int k0 = split * klen;
  __shared__ float As[16][64];
  __shared__ float Bs[16][64];
  int tid = threadIdx.x;
  int tx = tid & 15, ty = tid >> 4;
  int amm = tid >> 2, akk = (tid & 3) << 2;
  int bkk = tid >> 4, bnn = (tid & 15) << 2;
  float acc[4][4] = {{0.f}};
  for (int kt = k0; kt < k0 + klen; kt += 16) {
    float4 av = make_float4(0.f, 0.f, 0.f, 0.f);
    if (m0 + amm < p.M) av = *(const float4*)(A + (size_t)(m0 + amm) * p.K + kt + akk);
    float4 bv = *(const float4*)(B + (size_t)(kt + bkk) * 256 + n0 + bnn);
    __syncthreads();
    As[akk + 0][amm] = av.x;
    As[akk + 1][amm] = av.y;
    As[akk + 2][amm] = av.z;
    As[akk + 3][amm] = av.w;
    *(float4*)&Bs[bkk][bnn] = bv;
    __syncthreads();
#pragma unroll
    for (int kk = 0; kk < 16; kk++) {
      float4 a = *(const float4*)&As[kk][ty << 2];
      float4 b = *(const float4*)&Bs[kk][tx << 2];
      acc[0][0] += a.x * b.x; acc[0][1] += a.x * b.y; acc[0][2] += a.x * b.z; acc[0][3] += a.x * b.w;
      acc[1][0] += a.y * b.x; acc[1][1] += a.y * b.y; acc[1][2] += a.y * b.z; acc[1][3] += a.y * b.w;
      acc[2][0] += a.z * b.x; acc[2][1] += a.z * b.y; acc[2][2] += a.z * b.z; acc[2][3] += a.z * b.w;
      acc[3][0] += a.w * b.x; acc[3][1] += a.w * b.y; acc[3][2] += a.w * b.z; acc[3][3] += a.w * b.w;
    }
  }
  int rbase = m0 + (ty << 2), cbase = n0 + (tx << 2);
  if (p.atomic) {
#pragma unroll
    for (int i2 = 0; i2 < 4; i2++) {
      if (rbase + i2 < p.M) {
#pragma unroll
        for (int j2 = 0; j2 < 4; j2++)
          atomicAdd(&C[(size_t)(rbase + i2) * 256 + cbase + j2], acc[i2][j2]);
      }
    }
  } else {
#pragma unroll
    for (int i2 = 0; i2 < 4; i2++) {
      if (rbase + i2 < p.M)
        *(float4*)&C[(size_t)(rbase + i2) * 256 + cbase] =
            make_float4(acc[i2][0], acc[i2][1], acc[i2][2], acc[i2][3]);
    }
  }
  float* __restrict__ Ct = p.Ct[batch];
  if (Ct) {
#pragma unroll
    for (int i2 = 0; i2 < 4; i2++)
#pragma unroll
      for (int j2 = 0; j2 < 4; j2++)
        Ct[(size_t)(cbase + j2) * 256 + rbase + i2] = acc[i2][j2];
  }
}

// High-throughput fp32 GEMM: C[M][256] = A[M][K] @ B[K][256] (N fixed 256),
// BM=BN=128, BK=8, 256 threads, 8x8 micro-tile. Split-K writes partials to
// C + split*cstride (deterministic; no atomics).
__global__ __launch_bounds__(256) void gemm128(const float* __restrict__ A, const float* __restrict__ B,
                                               float* __restrict__ C, int M, int K, int ksplit,
                                               size_t cstride) {
  int m0 = blockIdx.x * 128, n0 = blockIdx.y * 128;
  int split = blockIdx.z;
  int klen = K / ksplit;
  int k0 = split * klen;
  float* __restrict__ Cw = C + (size_t)split * cstride;
  __shared__ float As[8][128];
  __shared__ float Bs[8][128];
  int tid = threadIdx.x;
  int am = tid >> 1, akc = (tid & 1) * 4;
  int bk = tid >> 5, bn = (tid & 31) * 4;
  int ty = tid >> 4, tx = tid & 15;
  float acc[8][8] = {{0.f}};
  for (int kt = k0; kt < k0 + klen; kt += 8) {
    float4 av = make_float4(0.f, 0.f, 0.f, 0.f);
    if (m0 + am < M) av = *(const float4*)(A + (size_t)(m0 + am) * K + kt + akc);
    float4 bv = *(const float4*)(B + (size_t)(kt + bk) * 256 + n0 + bn);
    __syncthreads();
    As[akc + 0][am] = av.x;
    As[akc + 1][am] = av.y;
    As[akc + 2][am] = av.z;
    As[akc + 3][am] = av.w;
    *(float4*)&Bs[bk][bn] = bv;
    __syncthreads();
#pragma unroll
    for (int kk = 0; kk < 8; kk++) {
      float4 a0 = *(const float4*)&As[kk][ty * 8];
      float4 a1 = *(const float4*)&As[kk][ty * 8 + 4];
      float4 b0 = *(const float4*)&Bs[kk][tx * 8];
      float4 b1 = *(const float4*)&Bs[kk][tx * 8 + 4];
      float ar[8] = {a0.x, a0.y, a0.z, a0.w, a1.x, a1.y, a1.z, a1.w};
      float br[8] = {b0.x, b0.y, b0.z, b0.w, b1.x, b1.y, b1.z, b1.w};
#pragma unroll
      for (int i = 0; i < 8; i++)
#pragma unroll
        for (int j = 0; j < 8; j++) acc[i][j] += ar[i] * br[j];
    }
  }
#pragma unroll
  for (int i = 0; i < 8; i++) {
    int row = m0 + ty * 8 + i;
    if (row < M) {
      *(float4*)&Cw[(size_t)row * 256 + n0 + tx * 8] = make_float4(acc[i][0], acc[i][1], acc[i][2], acc[i][3]);
      *(float4*)&Cw[(size_t)row * 256 + n0 + tx * 8 + 4] = make_float4(acc[i][4], acc[i][5], acc[i][6], acc[i][7]);
    }
  }
}

// dst[i] = sum over nsplit of src[s*elems + i]
__global__ __launch_bounds__(256) void reduce_splits(const float* __restrict__ src, float* __restrict__ dst,
                                                     int nsplit, int elems) {
  int idx = (blockIdx.x * 256 + threadIdx.x) * 4;
  if (idx >= elems) return;
  float4 a = make_float4(0.f, 0.f, 0.f, 0.f);
  for (int s = 0; s < nsplit; s++) {
    float4 v = *(const float4*)(src + (size_t)s * elems + idx);
    a.x += v.x; a.y += v.y; a.z += v.z; a.w += v.w;
  }
  *(float4*)(dst + idx) = a;
}

// Unit responses through one Dopri5 step: cols 0..255 -> R (also R^T into W1T
// slot 30), cols 256..383 -> Hermite-folded tap matrices, transposed, into FcatT.
__global__ __launch_bounds__(256) void unit_resp(const float* __restrict__ A,
                                                 const float* __restrict__ Bm,
                                                 float* __restrict__ Rout,
                                                 float* __restrict__ FcatT,
                                                 float* __restrict__ W1T) {
  int w = blockIdx.x;
  int i = threadIdx.x;
  __shared__ float xs4[256][4];

  const float AA[6][5] = {
      {0.f, 0.f, 0.f, 0.f, 0.f},
      {0.2f, 0.f, 0.f, 0.f, 0.f},
      {3.f / 40.f, 9.f / 40.f, 0.f, 0.f, 0.f},
      {44.f / 45.f, -56.f / 15.f, 32.f / 9.f, 0.f, 0.f},
      {19372.f / 6561.f, -25360.f / 2187.f, 64448.f / 6561.f, -212.f / 729.f, 0.f},
      {9017.f / 3168.f, -355.f / 33.f, 46732.f / 5247.f, 49.f / 176.f, -5103.f / 18656.f}};
  const float BB[6] = {35.f / 384.f, 0.f, 500.f / 1113.f, 125.f / 192.f, -2187.f / 6784.f, 11.f / 84.f};
  const float sv[6] = {0.f, 0.2f, 0.3f, 0.8f, 8.f / 9.f, 1.f};
  float Hm[6][4];
#pragma unroll
  for (int s = 0; s < 6; s++) {
    float ss = sv[s], s2 = ss * ss, s3 = s2 * ss;
    Hm[s][0] = 2.f * s3 - 3.f * s2 + 1.f;
    Hm[s][1] = s3 - 2.f * s2 + ss;
    Hm[s][2] = -2.f * s3 + 3.f * s2;
    Hm[s][3] = s3 - s2;
  }

  float xc[4];
  float kreg[6][4];
#pragma unroll
  for (int s = 0; s < 6; s++)
#pragma unroll
    for (int cc = 0; cc < 4; cc++) kreg[s][cc] = 0.f;

  int col[4], isF[4], tt[4];
  float brow[4];
#pragma unroll
  for (int cc = 0; cc < 4; cc++) {
    col[cc] = w * 4 + cc;
    if (col[cc] < 256) {
      isF[cc] = 0; tt[cc] = 0; brow[cc] = 0.f;
      xc[cc] = (i == col[cc]) ? 1.f : 0.f;
    } else {
      isF[cc] = 1; xc[cc] = 0.f;
      int f = col[cc] - 256;
      tt[cc] = f >> 5;
      brow[cc] = Bm[i * 32 + (f & 31)];
    }
  }
  float bh[6][4];
#pragma unroll
  for (int s = 0; s < 6; s++)
#pragma unroll
    for (int cc = 0; cc < 4; cc++) {
      float hv = (tt[cc] == 0) ? Hm[s][0] : ((tt[cc] == 1) ? Hm[s][1] : ((tt[cc] == 2) ? Hm[s][2] : Hm[s][3]));
      bh[s][cc] = isF[cc] ? hv * brow[cc] : 0.f;
    }

#pragma unroll
  for (int s = 0; s < 6; s++) {
#pragma unroll
    for (int cc = 0; cc < 4; cc++) {
      float v = xc[cc];
#pragma unroll
      for (int j = 0; j < 5; j++)
        if (j < s) v += AA[s][j] * kreg[j][cc];
      xs4[i][cc] = v;
    }
    __syncthreads();
    float ac[4] = {0.f, 0.f, 0.f, 0.f};
    for (int j = 0; j < 256; j += 4) {
      float4 ar = *(const float4*)(A + (size_t)i * 256 + j);
      float4 xa = *(const float4*)xs4[j + 0];
      float4 xb = *(const float4*)xs4[j + 1];
      float4 xv = *(const float4*)xs4[j + 2];
      float4 xd = *(const float4*)xs4[j + 3];
      ac[0] += ar.x * xa.x + ar.y * xb.x + ar.z * xv.x + ar.w * xd.x;
      ac[1] += ar.x * xa.y + ar.y * xb.y + ar.z * xv.y + ar.w * xd.y;
      ac[2] += ar.x * xa.z + ar.y * xb.z + ar.z * xv.z + ar.w * xd.z;
      ac[3] += ar.x * xa.w + ar.y * xb.w + ar.z * xv.w + ar.w * xd.w;
    }
#pragma unroll
    for (int cc = 0; cc < 4; cc++) kreg[s][cc] = ac[cc] + bh[s][cc];
    __syncthreads();
  }
#pragma unroll
  for (int cc = 0; cc < 4; cc++) {
    float o = xc[cc];
#pragma unroll
    for (int s = 0; s < 6; s++) o += BB[s] * kreg[s][cc];
    if (!isF[cc]) {
      Rout[(size_t)i * 256 + col[cc]] = o;
      W1T[(size_t)(30 * 256 + col[cc]) * 256 + i] = o;   // (R^1)^T -> W1T slot 30
    } else {
      FcatT[(size_t)(col[cc] - 256) * 256 + i] = o;
    }
  }
}

// Identity into W1T slot 31 and W2T slot 31.
__global__ __launch_bounds__(256) void id_fill(float* __restrict__ W1T, float* __restrict__ W2T) {
  float* dst = (blockIdx.x == 0 ? W1T : W2T) + (size_t)31 * 65536;
  int n = threadIdx.x;
  for (int r4 = 0; r4 < 256; r4 += 4) {
    float4 v = make_float4(r4 == n ? 1.f : 0.f, r4 + 1 == n ? 1.f : 0.f,
                           r4 + 2 == n ? 1.f : 0.f, r4 + 3 == n ? 1.f : 0.f);
    *(float4*)&dst[(size_t)n * 256 + r4] = v;
  }
}

// Wtap[n][tap] = {u_n, m_n, u_{n+1}, m_{n+1}} taps; row 32767 = 0 (pad).
__global__ __launch_bounds__(128) void build_wtap(const float* __restrict__ u, float* __restrict__ Wtap) {
  int n = blockIdx.x;
  int tid = threadIdx.x;
  int t = tid >> 5, c = tid & 31;
  float val = 0.f;
  if (n < TPTS - 1) {
    if (t == 0) val = u[(size_t)n * 32 + c];
    else if (t == 2) val = u[(size_t)(n + 1) * 32 + c];
    else {
      int k = (t == 1) ? n : n + 1;
      if (k == 0) val = u[32 + c] - u[c];
      else if (k == TPTS - 1) val = u[(size_t)(TPTS - 1) * 32 + c] - u[(size_t)(TPTS - 2) * 32 + c];
      else val = 0.5f * (u[(size_t)(k + 1) * 32 + c] - u[(size_t)(k - 1) * 32 + c]);
    }
  }
  Wtap[(size_t)n * 128 + tid] = val;
}

// Top-level (stride-1024) starts; ||R^1024|| ~ 6e-5 so 2-term series is exact enough.
__global__ __launch_bounds__(256) void top_scan(const float* __restrict__ V2, const float* __restrict__ x0,
                                                const float* __restrict__ R1024, float* __restrict__ X2) {
  int k = blockIdx.x, i = threadIdx.x;
  if (k == 0) { X2[i] = x0[i]; return; }
  __shared__ float prev[256];
  const float* pv = (k == 1) ? x0 : (V2 + (size_t)(k - 2) * 256);
  prev[i] = pv[i];
  __syncthreads();
  float acc = V2[(size_t)(k - 1) * 256 + i];
  const float* rr = R1024 + (size_t)i * 256;
  for (int j = 0; j < 256; j += 4) {
    float4 rv = *(const float4*)(rr + j);
    acc += rv.x * prev[j] + rv.y * prev[j + 1] + rv.z * prev[j + 2] + rv.w * prev[j + 3];
  }
  X2[(size_t)k * 256 + i] = acc;
}

// Expand one level: NCH chains per block, 31 steps x <- Rm x + v. Inner loop is
// vmem-FREE: V bulk-loaded into LDS per 12-row phase, outputs staged in LDS hist
// and bulk-stored per phase -> per-step barriers wait only lgkmcnt (no vmcnt
// drain of global loads/stores on the critical path — the round-3 stall).
// R slice (4 rows x 32 cols) in registers; x in bank-padded broadcast layout
// (8 unique float4 spread over all 32 banks, 8-way broadcast = free).
template <int NCH>
__global__ __launch_bounds__(512, 2) void expand_scan(const float* __restrict__ Rm,
                                                      const float* __restrict__ Xst,
                                                      const float* __restrict__ V,
                                                      float* __restrict__ Xout) {
  constexpr int CH = 12;   // rows per phase
  int blk = blockIdx.x;
  int t = threadIdx.x;
  int w = t >> 6, l = t & 63;
  int rg = l >> 3, cg = l & 7;
  int r0 = w * 32 + rg * 4;
  int c0 = cg * 32;
  float4 rr[4][8];
#pragma unroll
  for (int row = 0; row < 4; row++)
#pragma unroll
    for (int i = 0; i < 8; i++)
      rr[row][i] = *(const float4*)(Rm + (size_t)(r0 + row) * 256 + c0 + 4 * i);
  asm volatile("" ::: "memory");
  __shared__ float xbuf[2][NCH][288];          // padded: word f(q)=q+(q>>5)*4
  __shared__ float vbuf[CH][NCH][256];
  __shared__ float hist[CH][NCH][256];
  size_t gbase[NCH];
#pragma unroll
  for (int c = 0; c < NCH; c++) gbase[c] = ((size_t)blk * NCH + c) * 32 * 256;
  for (int e = t; e < NCH * 64; e += 512) {
    int c = e >> 6, q = (e & 63) * 4;
    float4 v4 = *(const float4*)(Xst + ((size_t)blk * NCH + c) * 256 + q);
    *(float4*)&xbuf[0][c][q + ((q >> 5) << 2)] = v4;
  }
  for (int ph = 0; ph < 3; ph++) {
    int rb = ph * CH;
    int nr = (32 - rb < CH) ? (32 - rb) : CH;   // rows this phase: 12,12,8
    int sb = (ph == 0) ? 0 : rb - 1;            // first step
    int se = rb + nr - 2;                       // last step (se<=30)
    int nv = se - sb + 1;
    for (int e = t; e < nv * NCH * 64; e += 512) {
      int jj = e / (NCH * 64);
      int r2 = e - jj * (NCH * 64);
      int c = r2 >> 6, q = (r2 & 63) * 4;
      *(float4*)&vbuf[jj][c][q] = *(const float4*)(V + gbase[c] + (size_t)(sb + jj) * 256 + q);
    }
    if (ph == 0) {
      for (int e = t; e < NCH * 64; e += 512) {
        int c = e >> 6, q = (e & 63) * 4;
        *(float4*)&hist[0][c][q] = *(const float4*)&xbuf[0][c][q + ((q >> 5) << 2)];
      }
    }
    __syncthreads();
    for (int s = sb; s <= se; s++) {
      float4 p[NCH];
#pragma unroll
      for (int c = 0; c < NCH; c++) p[c] = make_float4(0.f, 0.f, 0.f, 0.f);
#pragma unroll
      for (int i = 0; i < 8; i++) {
        int fi = cg * 36 + 4 * i;
#pragma unroll
        for (int c = 0; c < NCH; c++) {
          float4 xv = *(const float4*)&xbuf[s & 1][c][fi];
          p[c].x += rr[0][i].x * xv.x + rr[0][i].y * xv.y + rr[0][i].z * xv.z + rr[0][i].w * xv.w;
          p[c].y += rr[1][i].x * xv.x + rr[1][i].y * xv.y + rr[1][i].z * xv.z + rr[1][i].w * xv.w;
          p[c].z += rr[2][i].x * xv.x + rr[2][i].y * xv.y + rr[2][i].z * xv.z + rr[2][i].w * xv.w;
          p[c].w += rr[3][i].x * xv.x + rr[3][i].y * xv.y + rr[3][i].z * xv.z + rr[3][i].w * xv.w;
        }
      }
#pragma unroll
      for (int m = 1; m < 8; m <<= 1)
#pragma unroll
        for (int c = 0; c < NCH; c++) {
          p[c].x += __shfl_xor(p[c].x, m);
          p[c].y += __shfl_xor(p[c].y, m);
          p[c].z += __shfl_xor(p[c].z, m);
          p[c].w += __shfl_xor(p[c].w, m);
        }
      if (cg == 0) {
#pragma unroll
        for (int c = 0; c < NCH; c++) {
          float4 vd = *(const float4*)&vbuf[s - sb][c][r0];
          float4 nx = make_float4(p[c].x + vd.x, p[c].y + vd.y, p[c].z + vd.z, p[c].w + vd.w);
          *(float4*)&xbuf[(s + 1) & 1][c][w * 36 + rg * 4] = nx;
          *(float4*)&hist[s + 1 - rb][c][r0] = nx;
        }
      }
      __syncthreads();
    }
    for (int e = t; e < nr * NCH * 64; e += 512) {
      int jj = e / (NCH * 64);
      int r2 = e - jj * (NCH * 64);
      int c = r2 >> 6, q = (r2 & 63) * 4;
      *(float4*)(Xout + gbase[c] + (size_t)(rb + jj) * 256 + q) = *(const float4*)&hist[jj][c][q];
    }
    __syncthreads();
  }
}

// y = x @ C^T + u @ D^T
__global__ __launch_bounds__(256) void y_kernel(const float* __restrict__ x, const float* __restrict__ u,
                                                const float* __restrict__ Cm, const float* __restrict__ Dm,
                                                float* __restrict__ y) {
  __shared__ float Cs[32][260];
  __shared__ float Ds[32][32];
  __shared__ float xs[8][256];
  __shared__ float us[8][32];
  int tid = threadIdx.x;
  for (int k = tid; k < 8192; k += 256) Cs[k >> 8][k & 255] = Cm[k];
  for (int k = tid; k < 1024; k += 256) Ds[k >> 5][k & 31] = Dm[k];
  int o = tid & 31, rr = tid >> 5;
  int n0 = blockIdx.x * 64;
  for (int g = 0; g < 8; g++) {
    int nb = n0 + g * 8;
    __syncthreads();
    for (int k = tid; k < 2048; k += 256)
      xs[k >> 8][k & 255] = x[(size_t)(nb + (k >> 8)) * 256 + (k & 255)];
    for (int k = tid; k < 256; k += 256)
      us[k >> 5][k & 31] = u[(size_t)(nb + (k >> 5)) * 32 + (k & 31)];
    __syncthreads();
    float acc = 0.f;
    for (int i = 0; i < 256; i += 4) {
      float4 cv = *(const float4*)&Cs[o][i];
      float4 xv = *(const float4*)&xs[rr][i];
      acc += cv.x * xv.x + cv.y * xv.y + cv.z * xv.z + cv.w * xv.w;
    }
#pragma unroll
    for (int c = 0; c < 32; c += 4) {
      float4 dv = *(const float4*)&Ds[o][c];
      float4 uv = *(const float4*)&us[rr][c];
      acc += dv.x * uv.x + dv.y * uv.y + dv.z * uv.z + dv.w * uv.w;
    }
    y[(size_t)(nb + rr) * 32 + o] = acc;
  }
}

static void launch_gemm(hipStream_t s, int nb, const float* const* Aa, const float* const* Bb,
                        float* const* Cc, float* const* Ctt, int M, int K, int ksplit, int at) {
  GemmParams p;
  p.M = M; p.K = K; p.ksplit = ksplit; p.atomic = at;
  for (int i = 0; i < nb; i++) {
    p.A[i] = Aa[i]; p.B[i] = Bb[i]; p.C[i] = Cc[i];
    p.Ct[i] = Ctt ? Ctt[i] : nullptr;
  }
  for (int i = nb; i < 16; i++) { p.A[i] = nullptr; p.B[i] = nullptr; p.C[i] = nullptr; p.Ct[i] = nullptr; }
  dim3 g((M + 63) / 64, 4, nb * ksplit);
  gemm_f32<<<g, dim3(256), 0, s>>>(p);
}

extern "C" void kernel_launch(void* const* d_in, const int* in_sizes, int n_in,
                              void* d_out, int out_size, void* d_ws, size_t ws_size,
                              hipStream_t stream) {
  const float* u  = (const float*)d_in[1];
  const float* x0 = (const float*)d_in[2];
  const float* A  = (const float*)d_in[3];
  const float* Bm = (const float*)d_in[4];
  const float* Cm = (const float*)d_in[5];
  const float* Dm = (const float*)d_in[6];
  float* xout = (float*)d_out;                       // [32768][256]
  float* yout = xout + (size_t)TPTS * 256;           // [32768][32]

  char* wsb = (char*)d_ws;
  size_t off = 0;
  auto alloc = [&](size_t bytes) -> float* {
    float* p = (float*)(wsb + off);
    off = (off + bytes + 255) & ~(size_t)255;
    return p;
  };
  float* Rpow   = alloc(33ull * 65536 * 4);
  float* R32pow = alloc(33ull * 65536 * 4);
  float* FcatT  = alloc(128ull * 256 * 4);
  float* W1T    = alloc(8192ull * 256 * 4);
  float* W2T    = alloc(8192ull * 256 * 4);
  float* Wtap   = alloc((size_t)TPTS * 128 * 4);
  float* V0     = alloc((size_t)TPTS * 256 * 4);
  float* V1     = alloc(1024ull * 256 * 4);
  float* V1p    = alloc(16ull * 1024 * 256 * 4);
  float* V2     = alloc(32ull * 256 * 4);
  float* X2     = alloc(32ull * 256 * 4);
  float* X1     = alloc(1024ull * 256 * 4);
  (void)ws_size; (void)in_sizes; (void)n_in; (void)out_size;

  auto RP = [&](int p) -> float* { return Rpow + (size_t)p * 65536; };
  auto QP = [&](int p) -> float* { return R32pow + (size_t)p * 65536; };
  auto W1S = [&](int s) -> float* { return W1T + (size_t)s * 65536; };
  auto W2S = [&](int s) -> float* { return W2T + (size_t)s * 65536; };

  // 1. unit responses -> R (+R^T into W1T slot 30) and FcatT; identity slots
  unit_resp<<<dim3(96), dim3(256), 0, stream>>>(A, Bm, RP(1), FcatT, W1T);
  id_fill<<<dim3(2), dim3(256), 0, stream>>>(W1T, W2T);

  // 2. powers of R; transposed copies go straight into the W stacks (slot 31-p)
  {
    const float* a[16]; const float* b[16]; float* c[16]; float* ct[16];
    a[0] = RP(1); b[0] = RP(1); c[0] = RP(2); ct[0] = W1S(29);
    launch_gemm(stream, 1, a, b, c, ct, 256, 256, 1, 0);
    a[0] = RP(2); b[0] = RP(1); c[0] = RP(3); ct[0] = W1S(28);
    a[1] = RP(2); b[1] = RP(2); c[1] = RP(4); ct[1] = W1S(27);
    launch_gemm(stream, 2, a, b, c, ct, 256, 256, 1, 0);
    for (int k = 1; k <= 4; k++) { a[k-1] = RP(4); b[k-1] = RP(k); c[k-1] = RP(4+k); ct[k-1] = W1S(31-(4+k)); }
    launch_gemm(stream, 4, a, b, c, ct, 256, 256, 1, 0);
    for (int k = 1; k <= 8; k++) { a[k-1] = RP(8); b[k-1] = RP(k); c[k-1] = RP(8+k); ct[k-1] = W1S(31-(8+k)); }
    launch_gemm(stream, 8, a, b, c, ct, 256, 256, 1, 0);
    for (int k = 1; k <= 16; k++) {
      int pw = 16 + k;
      a[k-1] = RP(16); b[k-1] = RP(k); c[k-1] = RP(pw);
      ct[k-1] = (pw == 32) ? W2S(30) : W1S(31 - pw);     // R^32 = Q^1 -> W2T slot 30
    }
    launch_gemm(stream, 16, a, b, c, ct, 256, 256, 1, 0);
    // powers of R32 = Q
    auto QS = [&](int pp) -> const float* { return (pp == 1) ? (const float*)RP(32) : (const float*)QP(pp); };
    a[0] = QS(1); b[0] = QS(1); c[0] = QP(2); ct[0] = W2S(29);
    launch_gemm(stream, 1, a, b, c, ct, 256, 256, 1, 0);
    a[0] = QP(2); b[0] = QS(1); c[0] = QP(3); ct[0] = W2S(28);
    a[1] = QP(2); b[1] = QP(2); c[1] = QP(4); ct[1] = W2S(27);
    launch_gemm(stream, 2, a, b, c, ct, 256, 256, 1, 0);
    for (int k = 1; k <= 4; k++) { a[k-1] = QP(4); b[k-1] = QS(k); c[k-1] = QP(4+k); ct[k-1] = W2S(31-(4+k)); }
    launch_gemm(stream, 4, a, b, c, ct, 256, 256, 1, 0);
    for (int k = 1; k <= 8; k++) { a[k-1] = QP(8); b[k-1] = QS(k); c[k-1] = QP(8+k); ct[k-1] = W2S(31-(8+k)); }
    launch_gemm(stream, 8, a, b, c, ct, 256, 256, 1, 0);
    for (int k = 1; k <= 16; k++) {
      int pw = 16 + k;
      a[k-1] = QP(16); b[k-1] = QS(k); c[k-1] = QP(pw);
      ct[k-1] = (pw == 32) ? nullptr : W2S(31 - pw);     // Q^32 = R^1024: no transpose needed
    }
    launch_gemm(stream, 16, a, b, c, ct, 256, 256, 1, 0);
  }

  // 3. Hermite taps and per-step drive v_n
  build_wtap<<<dim3(TPTS), dim3(128), 0, stream>>>(u, Wtap);
  gemm128<<<dim3(256, 2, 1), dim3(256), 0, stream>>>(Wtap, FcatT, V0, TPTS, 128, 1, 0);

  // 4. level-1 reduce: V1[j] = sum_i R^(31-i) v_{32j+i}  (split-K=16, deterministic)
  gemm128<<<dim3(8, 2, 16), dim3(256), 0, stream>>>(V0, W1T, V1p, 1024, 8192, 16, (size_t)1024 * 256);
  reduce_splits<<<dim3(256), dim3(256), 0, stream>>>(V1p, V1, 16, 1024 * 256);

  // 5. level-2 reduce: V2[k] = sum_j Q^(31-j) V1[32k+j]
  hipMemsetAsync(V2, 0, 32ull * 256 * 4, stream);
  {
    const float* a[1] = {V1}; const float* b[1] = {W2T}; float* c[1] = {V2};
    launch_gemm(stream, 1, a, b, c, nullptr, 32, 8192, 8, 1);
  }

  // 6. top starts, then expand down two levels
  top_scan<<<dim3(32), dim3(256), 0, stream>>>(V2, x0, QP(32), X2);
  expand_scan<1><<<dim3(32), dim3(512), 0, stream>>>(RP(32), X2, V1, X1);
  expand_scan<2><<<dim3(512), dim3(512), 0, stream>>>(RP(1), X1, V0, xout);

  // 7. outputs y
  y_kernel<<<dim3(512), dim3(256), 0, stream>>>(xout, u, Cm, Dm, yout);
}